// Round 1
// baseline (333.269 us; speedup 1.0000x reference)
//
#include <hip/hip_runtime.h>
#include <hip/hip_bf16.h>
#include <stdint.h>

#define N_NODES 50000
#define N_EDGES 800000
#define D 128
#define NPAD 50048
#define KDIM 512

typedef __attribute__((ext_vector_type(8))) __bf16 bf16x8;
typedef __attribute__((ext_vector_type(4))) __bf16 bf16x4;
typedef __attribute__((ext_vector_type(4))) float f32x4;

__device__ __forceinline__ void gload_lds16(const void* g, void* l) {
  __builtin_amdgcn_global_load_lds(
      (const __attribute__((address_space(1))) unsigned int*)(uintptr_t)g,
      (__attribute__((address_space(3))) unsigned int*)(uint32_t)(uintptr_t)l,
      16, 0, 0);
}

__device__ __forceinline__ float sigm(float v) { return 1.0f / (1.0f + __expf(-v)); }
__device__ __forceinline__ float tanh_fast(float v) { return 1.0f - 2.0f / (1.0f + __expf(2.0f * v)); }

// ---------------- degree count ----------------
__global__ void k_deg(const int* __restrict__ dst, int* __restrict__ deg) {
  int e = blockIdx.x * 256 + threadIdx.x;
  if (e < N_EDGES) atomicAdd(&deg[dst[e]], 1);
}

// ---------------- single-block exclusive scan (50000 ints, 4/thread/iter) ----------------
__global__ void k_scan(const int* __restrict__ deg, int* __restrict__ offs,
                       int* __restrict__ cursor, int n) {
  const int t = threadIdx.x;
  const int lane = t & 63;
  const int w = t >> 6;
  __shared__ int wsum[4];
  __shared__ int carry_s;
  int carry = 0;
  for (int base = 0; base < n; base += 1024) {
    int idx = base + t * 4;
    int4 v = make_int4(0, 0, 0, 0);
    if (idx < n) v = *(const int4*)(deg + idx);  // n % 4 == 0, safe
    int tsum = v.x + v.y + v.z + v.w;
    int s = tsum;
#pragma unroll
    for (int d = 1; d < 64; d <<= 1) {
      int u = __shfl_up(s, d, 64);
      if (lane >= d) s += u;
    }
    if (lane == 63) wsum[w] = s;
    __syncthreads();
    int woff = 0;
    for (int i = 0; i < w; i++) woff += wsum[i];
    int excl = carry + woff + (s - tsum);
    if (idx < n) {
      int4 o;
      o.x = excl; o.y = excl + v.x; o.z = o.y + v.y; o.w = o.z + v.z;
      *(int4*)(offs + idx) = o;
      *(int4*)(cursor + idx) = o;
    }
    __syncthreads();
    if (t == 0) carry_s = carry + wsum[0] + wsum[1] + wsum[2] + wsum[3];
    __syncthreads();
    carry = carry_s;
  }
  if (t == 0) offs[n] = carry;  // total = N_EDGES
}

// ---------------- fill CSR bins ----------------
__global__ void k_fill(const int* __restrict__ src, const int* __restrict__ dst,
                       int* __restrict__ cursor, int* __restrict__ bins) {
  int e = blockIdx.x * 256 + threadIdx.x;
  if (e < N_EDGES) {
    int d = dst[e];
    int p = atomicAdd(&cursor[d], 1);
    bins[p] = src[e];
  }
}

// ---------------- gather means + build fused bf16 input Z = [x | mean_x | h | mean_h] ----------------
__global__ void k_gather(const float* __restrict__ x, const float* __restrict__ h,
                         const int* __restrict__ offs, const int* __restrict__ bins,
                         __bf16* __restrict__ Z) {
  int wid = (blockIdx.x * 256 + threadIdx.x) >> 6;
  int lane = threadIdx.x & 63;
  if (wid >= NPAD) return;
  __bf16* zrow = Z + (size_t)wid * KDIM;
  if (wid >= N_NODES) {  // zero the pad rows
    for (int q = lane; q < 128; q += 64) ((unsigned int*)zrow)[q] = 0;
    return;
  }
  const float* base = (lane < 32) ? x : h;  // lanes 0-31: x feats, 32-63: h feats
  int l31 = lane & 31;
  int beg = offs[wid], end = offs[wid + 1];
  float ax = 0.f, ay = 0.f, az = 0.f, aw = 0.f;
  for (int j = beg; j < end; ++j) {
    int s = bins[j];
    float4 v = *(const float4*)(base + (size_t)s * D + 4 * l31);
    ax += v.x; ay += v.y; az += v.z; aw += v.w;
  }
  int degn = end - beg;
  float inv = 1.0f / (float)(degn > 0 ? degn : 1);
  float4 sv = *(const float4*)(base + (size_t)wid * D + 4 * l31);
  int col_self = ((lane < 32) ? 0 : 256) + 4 * l31;
  int col_agg = ((lane < 32) ? 128 : 384) + 4 * l31;
  bf16x4 a, b;
  a[0] = (__bf16)sv.x; a[1] = (__bf16)sv.y; a[2] = (__bf16)sv.z; a[3] = (__bf16)sv.w;
  b[0] = (__bf16)(ax * inv); b[1] = (__bf16)(ay * inv);
  b[2] = (__bf16)(az * inv); b[3] = (__bf16)(aw * inv);
  *(bf16x4*)(zrow + col_self) = a;
  *(bf16x4*)(zrow + col_agg) = b;
}

// ---------------- pack 16 weight matrices into bf16 W[n=g*128+o][k=512] ----------------
__global__ void k_packw(const float* __restrict__ Wx_self, const float* __restrict__ Wx_neigh,
                        const float* __restrict__ Wh_self, const float* __restrict__ Wh_neigh,
                        __bf16* __restrict__ W) {
  int idx = blockIdx.x * 256 + threadIdx.x;  // 512*512
  int nq = idx >> 9, k = idx & 511;
  int g = nq >> 7, o = nq & 127;
  int i = k & 127;
  const float* s;
  if (k < 128) s = Wx_self;
  else if (k < 256) s = Wx_neigh;
  else if (k < 384) s = Wh_self;
  else s = Wh_neigh;
  W[idx] = (__bf16)s[(g << 14) + (i << 7) + o];
}

// ---------------- fused GEMM (Z[NPAD,512] @ W^T[512,512]) + LSTM gates epilogue ----------------
// Block: 512 threads (8 waves), BM=64, BN=512 (all 4 gates), BK=32.
// Wave w owns output features o = w*16 + (lane&15); B-frag g gives gate g for those o.
__global__ __launch_bounds__(512) void k_gemm(
    const __bf16* __restrict__ Z, const __bf16* __restrict__ W,
    const float* __restrict__ c,
    const float* __restrict__ w_ci, const float* __restrict__ w_cf, const float* __restrict__ w_co,
    const float* __restrict__ b_i, const float* __restrict__ b_f, const float* __restrict__ b_c,
    const float* __restrict__ b_o,
    float* __restrict__ out_h, float* __restrict__ out_c) {
  __shared__ __align__(16) __bf16 As[64 * 32];   // [row][k], XOR-4 swizzled
  __shared__ __align__(16) __bf16 Bs[512 * 32];  // [n][k],   XOR-4 swizzled
  const int t = threadIdx.x;
  const int lane = t & 63;
  const int w = t >> 6;
  const int m0 = blockIdx.x * 64;
  const int l15 = lane & 15;
  const int q = lane >> 4;  // 0..3

  f32x4 acc[4][4];
#pragma unroll
  for (int m = 0; m < 4; ++m)
#pragma unroll
    for (int g = 0; g < 4; ++g) acc[m][g] = (f32x4){0.f, 0.f, 0.f, 0.f};

  // A staging map (t<256): row=t>>2, 16B slot=t&3, source k pre-swizzled
  const int arow = t >> 2, aslot = t & 3;
  const __bf16* aSrc = Z + (size_t)(m0 + arow) * KDIM + ((aslot ^ (arow & 3)) << 3);
  __bf16* aDst = (__bf16*)As + t * 8;

  for (int k0 = 0; k0 < KDIM; k0 += 32) {
    if (t < 256) gload_lds16(aSrc + k0, aDst);
#pragma unroll
    for (int j = 0; j < 4; ++j) {
      int line = j * 512 + t;
      int brow = line >> 2, bslot = line & 3;
      gload_lds16(W + (size_t)brow * KDIM + k0 + ((bslot ^ (brow & 3)) << 3),
                  (__bf16*)Bs + line * 8);
    }
    __syncthreads();  // compiler drains vmcnt before barrier

    bf16x8 af[4], bfr[4];
#pragma unroll
    for (int m = 0; m < 4; ++m) {
      int row = m * 16 + l15;
      af[m] = *(const bf16x8*)(As + row * 32 + ((q ^ (row & 3)) << 3));
    }
#pragma unroll
    for (int g = 0; g < 4; ++g) {
      int n = g * 128 + w * 16 + l15;
      bfr[g] = *(const bf16x8*)(Bs + n * 32 + ((q ^ (n & 3)) << 3));
    }
#pragma unroll
    for (int m = 0; m < 4; ++m)
#pragma unroll
      for (int g = 0; g < 4; ++g)
        acc[m][g] = __builtin_amdgcn_mfma_f32_16x16x32_bf16(af[m], bfr[g], acc[m][g], 0, 0, 0);
    __syncthreads();
  }

  // epilogue: LSTM cell math, fused
  const int o = w * 16 + l15;
  const float wci = w_ci[o], wcf = w_cf[o], wco = w_co[o];
  const float bi = b_i[o], bfv = b_f[o], bc = b_c[o], bo = b_o[o];
#pragma unroll
  for (int m = 0; m < 4; ++m) {
#pragma unroll
    for (int r = 0; r < 4; ++r) {
      int row = m0 + m * 16 + q * 4 + r;
      if (row < N_NODES) {
        float cv = c[(size_t)row * D + o];
        float ig = sigm(acc[m][0][r] + wci * cv + bi);
        float fg = sigm(acc[m][1][r] + wcf * cv + bfv);
        float ct = tanh_fast(acc[m][2][r] + bc);
        float nc = fg * cv + ig * ct;
        float og = sigm(acc[m][3][r] + wco * nc + bo);
        out_h[(size_t)row * D + o] = og * tanh_fast(nc);
        out_c[(size_t)row * D + o] = nc;
      }
    }
  }
}

extern "C" void kernel_launch(void* const* d_in, const int* in_sizes, int n_in,
                              void* d_out, int out_size, void* d_ws, size_t ws_size,
                              hipStream_t stream) {
  const float* x = (const float*)d_in[0];
  const float* h = (const float*)d_in[1];
  const float* c = (const float*)d_in[2];
  const float* Wx_self = (const float*)d_in[3];
  const float* Wx_neigh = (const float*)d_in[4];
  const float* Wh_self = (const float*)d_in[5];
  const float* Wh_neigh = (const float*)d_in[6];
  const float* w_ci = (const float*)d_in[7];
  const float* w_cf = (const float*)d_in[8];
  const float* w_co = (const float*)d_in[9];
  const float* b_i = (const float*)d_in[10];
  const float* b_f = (const float*)d_in[11];
  const float* b_c = (const float*)d_in[12];
  const float* b_o = (const float*)d_in[13];
  const int* src = (const int*)d_in[14];
  const int* dst = (const int*)d_in[15];

  char* ws = (char*)d_ws;
  int* deg = (int*)(ws);                    // 50000 ints
  int* offs = (int*)(ws + 200704);          // 50001 ints
  int* cursor = (int*)(ws + 400896);        // 50000 ints
  int* bins = (int*)(ws + 601088);          // 800000 ints
  __bf16* Z = (__bf16*)(ws + 4194304);      // [50048][512] bf16 = 51.25 MB
  __bf16* W = (__bf16*)(ws + 55443456);     // [512][512] bf16

  float* out_h = (float*)d_out;
  float* out_c = out_h + (size_t)N_NODES * D;

  hipMemsetAsync(deg, 0, N_NODES * sizeof(int), stream);
  k_deg<<<(N_EDGES + 255) / 256, 256, 0, stream>>>(dst, deg);
  k_scan<<<1, 256, 0, stream>>>(deg, offs, cursor, N_NODES);
  k_fill<<<(N_EDGES + 255) / 256, 256, 0, stream>>>(src, dst, cursor, bins);
  k_gather<<<NPAD / 4, 256, 0, stream>>>(x, h, offs, bins, Z);
  k_packw<<<(512 * 512) / 256, 256, 0, stream>>>(Wx_self, Wx_neigh, Wh_self, Wh_neigh, W);
  k_gemm<<<NPAD / 64, 512, 0, stream>>>(Z, W, c, w_ci, w_cf, w_co,
                                        b_i, b_f, b_c, b_o, out_h, out_c);
}

// Round 2
// 285.482 us; speedup vs baseline: 1.1674x; 1.1674x over previous
//
#include <hip/hip_runtime.h>
#include <hip/hip_bf16.h>
#include <stdint.h>

#define N_NODES 50000
#define N_EDGES 800000
#define D 128
#define NPAD 50048
#define KDIM 512

typedef __attribute__((ext_vector_type(8))) __bf16 bf16x8;
typedef __attribute__((ext_vector_type(4))) __bf16 bf16x4;
typedef __attribute__((ext_vector_type(4))) float f32x4;

__device__ __forceinline__ void gload_lds16(const void* g, void* l) {
  __builtin_amdgcn_global_load_lds(
      (const __attribute__((address_space(1))) unsigned int*)(uintptr_t)g,
      (__attribute__((address_space(3))) unsigned int*)(uint32_t)(uintptr_t)l,
      16, 0, 0);
}

__device__ __forceinline__ float sigm(float v) { return 1.0f / (1.0f + __expf(-v)); }
__device__ __forceinline__ float tanh_fast(float v) { return 1.0f - 2.0f / (1.0f + __expf(2.0f * v)); }

// ---------------- degree count ----------------
__global__ void k_deg(const int* __restrict__ dst, int* __restrict__ deg) {
  int e = blockIdx.x * 256 + threadIdx.x;
  if (e < N_EDGES) atomicAdd(&deg[dst[e]], 1);
}

// ---------------- single-block exclusive scan (50000 ints, 1024 thr, 4/thread/iter) ----------------
__global__ __launch_bounds__(1024) void k_scan(const int* __restrict__ deg, int* __restrict__ offs,
                                               int* __restrict__ cursor, int n) {
  const int t = threadIdx.x;
  const int lane = t & 63;
  const int w = t >> 6;  // 0..15
  __shared__ int wsum[16];
  __shared__ int carry_s;
  int carry = 0;
  for (int base = 0; base < n; base += 4096) {
    int idx = base + t * 4;
    int4 v = make_int4(0, 0, 0, 0);
    if (idx < n) v = *(const int4*)(deg + idx);  // n % 4 == 0, safe
    int tsum = v.x + v.y + v.z + v.w;
    int s = tsum;
#pragma unroll
    for (int d = 1; d < 64; d <<= 1) {
      int u = __shfl_up(s, d, 64);
      if (lane >= d) s += u;
    }
    if (lane == 63) wsum[w] = s;
    __syncthreads();
    int woff = 0;
    for (int i = 0; i < w; i++) woff += wsum[i];
    int excl = carry + woff + (s - tsum);
    if (idx < n) {
      int4 o;
      o.x = excl; o.y = excl + v.x; o.z = o.y + v.y; o.w = o.z + v.z;
      *(int4*)(offs + idx) = o;
      *(int4*)(cursor + idx) = o;
    }
    __syncthreads();
    if (t == 0) {
      int tot = carry;
#pragma unroll
      for (int i = 0; i < 16; i++) tot += wsum[i];
      carry_s = tot;
    }
    __syncthreads();
    carry = carry_s;
  }
  if (t == 0) offs[n] = carry;  // total = N_EDGES
}

// ---------------- fill CSR bins ----------------
__global__ void k_fill(const int* __restrict__ src, const int* __restrict__ dst,
                       int* __restrict__ cursor, int* __restrict__ bins) {
  int e = blockIdx.x * 256 + threadIdx.x;
  if (e < N_EDGES) {
    int d = dst[e];
    int p = atomicAdd(&cursor[d], 1);
    bins[p] = src[e];
  }
}

// ---------------- fp32 x,h -> bf16 self columns of Z ----------------
// Z row layout: [ x_self(128) | mean_x(128) | h_self(128) | mean_h(128) ]
__global__ void k_tobf16(const float* __restrict__ x, const float* __restrict__ h,
                         __bf16* __restrict__ Z) {
  int idx = blockIdx.x * 256 + threadIdx.x;  // 1.6M threads, 4 feats each
  if (idx >= (N_NODES * D) / 4) return;
  int node = idx >> 5;
  int f4 = (idx & 31) << 2;
  float4 xv = *(const float4*)(x + (size_t)node * D + f4);
  float4 hv = *(const float4*)(h + (size_t)node * D + f4);
  bf16x4 a, b;
  a[0] = (__bf16)xv.x; a[1] = (__bf16)xv.y; a[2] = (__bf16)xv.z; a[3] = (__bf16)xv.w;
  b[0] = (__bf16)hv.x; b[1] = (__bf16)hv.y; b[2] = (__bf16)hv.z; b[3] = (__bf16)hv.w;
  __bf16* zrow = Z + (size_t)node * KDIM;
  *(bf16x4*)(zrow + f4) = a;
  *(bf16x4*)(zrow + 256 + f4) = b;
}

// ---------------- gather means from bf16 self cols -> agg cols of Z ----------------
__global__ void k_gather(const int* __restrict__ offs, const int* __restrict__ bins,
                         __bf16* __restrict__ Z) {
  int wid = (blockIdx.x * 256 + threadIdx.x) >> 6;
  int lane = threadIdx.x & 63;
  if (wid >= NPAD) return;
  __bf16* zrow = Z + (size_t)wid * KDIM;
  if (wid >= N_NODES) {  // zero the pad rows entirely (1024 B)
    for (int q = lane; q < 256; q += 64) ((unsigned int*)zrow)[q] = 0;
    return;
  }
  // lanes 0-31: x feats (self cols 0..127), lanes 32-63: h feats (self cols 256..383)
  const int srcoff = ((lane < 32) ? 0 : 256) + 4 * (lane & 31);
  int beg = offs[wid], end = offs[wid + 1];
  float a0 = 0.f, a1 = 0.f, a2 = 0.f, a3 = 0.f;
  for (int j = beg; j < end; ++j) {
    int s = bins[j];
    bf16x4 v = *(const bf16x4*)(Z + (size_t)s * KDIM + srcoff);
    a0 += (float)v[0]; a1 += (float)v[1]; a2 += (float)v[2]; a3 += (float)v[3];
  }
  int degn = end - beg;
  float inv = 1.0f / (float)(degn > 0 ? degn : 1);
  bf16x4 b;
  b[0] = (__bf16)(a0 * inv); b[1] = (__bf16)(a1 * inv);
  b[2] = (__bf16)(a2 * inv); b[3] = (__bf16)(a3 * inv);
  *(bf16x4*)(zrow + srcoff + 128) = b;  // agg col = self col + 128
}

// ---------------- pack 16 weight matrices into bf16 W[n=g*128+o][k=512] ----------------
__global__ void k_packw(const float* __restrict__ Wx_self, const float* __restrict__ Wx_neigh,
                        const float* __restrict__ Wh_self, const float* __restrict__ Wh_neigh,
                        __bf16* __restrict__ W) {
  int idx = blockIdx.x * 256 + threadIdx.x;  // 512*512
  int nq = idx >> 9, k = idx & 511;
  int g = nq >> 7, o = nq & 127;
  int i = k & 127;
  const float* s;
  if (k < 128) s = Wx_self;
  else if (k < 256) s = Wx_neigh;
  else if (k < 384) s = Wh_self;
  else s = Wh_neigh;
  W[idx] = (__bf16)s[(g << 14) + (i << 7) + o];
}

// ---------------- fused GEMM (Z[NPAD,512] @ W^T[512,512]) + LSTM gates epilogue ----------------
// Block: 512 threads (8 waves), BM=64, BN=512 (all 4 gates), BK=32.
// Wave w owns output features o = w*16 + (lane&15); B-frag g gives gate g for those o.
__global__ __launch_bounds__(512) void k_gemm(
    const __bf16* __restrict__ Z, const __bf16* __restrict__ W,
    const float* __restrict__ c,
    const float* __restrict__ w_ci, const float* __restrict__ w_cf, const float* __restrict__ w_co,
    const float* __restrict__ b_i, const float* __restrict__ b_f, const float* __restrict__ b_c,
    const float* __restrict__ b_o,
    float* __restrict__ out_h, float* __restrict__ out_c) {
  __shared__ __align__(16) __bf16 As[64 * 32];   // [row][k], XOR-4 swizzled
  __shared__ __align__(16) __bf16 Bs[512 * 32];  // [n][k],   XOR-4 swizzled
  const int t = threadIdx.x;
  const int lane = t & 63;
  const int w = t >> 6;
  const int m0 = blockIdx.x * 64;
  const int l15 = lane & 15;
  const int q = lane >> 4;  // 0..3

  f32x4 acc[4][4];
#pragma unroll
  for (int m = 0; m < 4; ++m)
#pragma unroll
    for (int g = 0; g < 4; ++g) acc[m][g] = (f32x4){0.f, 0.f, 0.f, 0.f};

  // A staging map (t<256): row=t>>2, 16B slot=t&3, source k pre-swizzled
  const int arow = t >> 2, aslot = t & 3;
  const __bf16* aSrc = Z + (size_t)(m0 + arow) * KDIM + ((aslot ^ (arow & 3)) << 3);
  __bf16* aDst = (__bf16*)As + t * 8;

  for (int k0 = 0; k0 < KDIM; k0 += 32) {
    if (t < 256) gload_lds16(aSrc + k0, aDst);
#pragma unroll
    for (int j = 0; j < 4; ++j) {
      int line = j * 512 + t;
      int brow = line >> 2, bslot = line & 3;
      gload_lds16(W + (size_t)brow * KDIM + k0 + ((bslot ^ (brow & 3)) << 3),
                  (__bf16*)Bs + line * 8);
    }
    __syncthreads();  // compiler drains vmcnt before barrier

    bf16x8 af[4], bfr[4];
#pragma unroll
    for (int m = 0; m < 4; ++m) {
      int row = m * 16 + l15;
      af[m] = *(const bf16x8*)(As + row * 32 + ((q ^ (row & 3)) << 3));
    }
#pragma unroll
    for (int g = 0; g < 4; ++g) {
      int n = g * 128 + w * 16 + l15;
      bfr[g] = *(const bf16x8*)(Bs + n * 32 + ((q ^ (n & 3)) << 3));
    }
#pragma unroll
    for (int m = 0; m < 4; ++m)
#pragma unroll
      for (int g = 0; g < 4; ++g)
        acc[m][g] = __builtin_amdgcn_mfma_f32_16x16x32_bf16(af[m], bfr[g], acc[m][g], 0, 0, 0);
    __syncthreads();
  }

  // epilogue: LSTM cell math, fused
  const int o = w * 16 + l15;
  const float wci = w_ci[o], wcf = w_cf[o], wco = w_co[o];
  const float bi = b_i[o], bfv = b_f[o], bc = b_c[o], bo = b_o[o];
#pragma unroll
  for (int m = 0; m < 4; ++m) {
#pragma unroll
    for (int r = 0; r < 4; ++r) {
      int row = m0 + m * 16 + q * 4 + r;
      if (row < N_NODES) {
        float cv = c[(size_t)row * D + o];
        float ig = sigm(acc[m][0][r] + wci * cv + bi);
        float fg = sigm(acc[m][1][r] + wcf * cv + bfv);
        float ct = tanh_fast(acc[m][2][r] + bc);
        float nc = fg * cv + ig * ct;
        float og = sigm(acc[m][3][r] + wco * nc + bo);
        out_h[(size_t)row * D + o] = og * tanh_fast(nc);
        out_c[(size_t)row * D + o] = nc;
      }
    }
  }
}

extern "C" void kernel_launch(void* const* d_in, const int* in_sizes, int n_in,
                              void* d_out, int out_size, void* d_ws, size_t ws_size,
                              hipStream_t stream) {
  const float* x = (const float*)d_in[0];
  const float* h = (const float*)d_in[1];
  const float* c = (const float*)d_in[2];
  const float* Wx_self = (const float*)d_in[3];
  const float* Wx_neigh = (const float*)d_in[4];
  const float* Wh_self = (const float*)d_in[5];
  const float* Wh_neigh = (const float*)d_in[6];
  const float* w_ci = (const float*)d_in[7];
  const float* w_cf = (const float*)d_in[8];
  const float* w_co = (const float*)d_in[9];
  const float* b_i = (const float*)d_in[10];
  const float* b_f = (const float*)d_in[11];
  const float* b_c = (const float*)d_in[12];
  const float* b_o = (const float*)d_in[13];
  const int* src = (const int*)d_in[14];
  const int* dst = (const int*)d_in[15];

  char* ws = (char*)d_ws;
  int* deg = (int*)(ws);                    // 50000 ints
  int* offs = (int*)(ws + 200704);          // 50001 ints
  int* cursor = (int*)(ws + 400896);        // 50000 ints
  int* bins = (int*)(ws + 601088);          // 800000 ints
  __bf16* Z = (__bf16*)(ws + 4194304);      // [50048][512] bf16 = 51.25 MB
  __bf16* W = (__bf16*)(ws + 55443456);     // [512][512] bf16

  float* out_h = (float*)d_out;
  float* out_c = out_h + (size_t)N_NODES * D;

  hipMemsetAsync(deg, 0, N_NODES * sizeof(int), stream);
  k_deg<<<(N_EDGES + 255) / 256, 256, 0, stream>>>(dst, deg);
  k_scan<<<1, 1024, 0, stream>>>(deg, offs, cursor, N_NODES);
  k_fill<<<(N_EDGES + 255) / 256, 256, 0, stream>>>(src, dst, cursor, bins);
  k_tobf16<<<((N_NODES * D / 4) + 255) / 256, 256, 0, stream>>>(x, h, Z);
  k_gather<<<NPAD / 4, 256, 0, stream>>>(offs, bins, Z);
  k_packw<<<(512 * 512) / 256, 256, 0, stream>>>(Wx_self, Wx_neigh, Wh_self, Wh_neigh, W);
  k_gemm<<<NPAD / 64, 512, 0, stream>>>(Z, W, c, w_ci, w_cf, w_co,
                                        b_i, b_f, b_c, b_o, out_h, out_c);
}

// Round 3
// 268.035 us; speedup vs baseline: 1.2434x; 1.0651x over previous
//
#include <hip/hip_runtime.h>
#include <hip/hip_bf16.h>
#include <stdint.h>

#define N_NODES 50000
#define N_EDGES 800000
#define D 128
#define NPAD 50048
#define KDIM 512

typedef __attribute__((ext_vector_type(8))) __bf16 bf16x8;
typedef __attribute__((ext_vector_type(4))) __bf16 bf16x4;
typedef __attribute__((ext_vector_type(4))) float f32x4;

__device__ __forceinline__ void gload_lds16(const void* g, void* l) {
  __builtin_amdgcn_global_load_lds(
      (const __attribute__((address_space(1))) unsigned int*)(uintptr_t)g,
      (__attribute__((address_space(3))) unsigned int*)(uint32_t)(uintptr_t)l,
      16, 0, 0);
}

__device__ __forceinline__ float sigm(float v) { return 1.0f / (1.0f + __expf(-v)); }
__device__ __forceinline__ float tanh_fast(float v) { return 1.0f - 2.0f / (1.0f + __expf(2.0f * v)); }

// ---------------- merged prep: deg count + fp32->bf16 self cols + weight pack ----------------
// Z row layout: [ x_self(0-127) | h_self(128-255) | mean_x(256-383) | mean_h(384-511) ]
// W[n=g*128+o][k]: k<128 -> Wx_self, <256 -> Wh_self, <384 -> Wx_neigh, else Wh_neigh
#define NB_DEG 3125   // 800000/256
#define NB_TOB 6250   // 1600000/256
#define NB_PKW 1024   // 262144/256
__global__ void k_pre(const int* __restrict__ dst, int* __restrict__ deg,
                      const float* __restrict__ x, const float* __restrict__ h,
                      __bf16* __restrict__ Z,
                      const float* __restrict__ Wx_self, const float* __restrict__ Wx_neigh,
                      const float* __restrict__ Wh_self, const float* __restrict__ Wh_neigh,
                      __bf16* __restrict__ W) {
  int b = blockIdx.x;
  if (b < NB_DEG) {
    int e = b * 256 + threadIdx.x;
    atomicAdd(&deg[dst[e]], 1);  // grid exact: 3125*256 == 800000
  } else if (b < NB_DEG + NB_TOB) {
    int idx = (b - NB_DEG) * 256 + threadIdx.x;  // 1.6M threads, 4 feats each
    int node = idx >> 5;
    int f4 = (idx & 31) << 2;
    float4 xv = *(const float4*)(x + (size_t)node * D + f4);
    float4 hv = *(const float4*)(h + (size_t)node * D + f4);
    bf16x4 a, bb;
    a[0] = (__bf16)xv.x; a[1] = (__bf16)xv.y; a[2] = (__bf16)xv.z; a[3] = (__bf16)xv.w;
    bb[0] = (__bf16)hv.x; bb[1] = (__bf16)hv.y; bb[2] = (__bf16)hv.z; bb[3] = (__bf16)hv.w;
    __bf16* zrow = Z + (size_t)node * KDIM;
    *(bf16x4*)(zrow + f4) = a;
    *(bf16x4*)(zrow + 128 + f4) = bb;
  } else {
    int idx = (b - NB_DEG - NB_TOB) * 256 + threadIdx.x;  // 512*512
    int nq = idx >> 9, k = idx & 511;
    int g = nq >> 7, o = nq & 127;
    const float* s; int i;
    if (k < 128)      { s = Wx_self;  i = k; }
    else if (k < 256) { s = Wh_self;  i = k - 128; }
    else if (k < 384) { s = Wx_neigh; i = k - 256; }
    else              { s = Wh_neigh; i = k - 384; }
    W[idx] = (__bf16)s[(g << 14) + (i << 7) + o];
  }
}

// ---------------- single-block exclusive scan (50000 ints, 1024 thr) ----------------
__global__ __launch_bounds__(1024) void k_scan(const int* __restrict__ deg, int* __restrict__ offs,
                                               int* __restrict__ cursor, int n) {
  const int t = threadIdx.x;
  const int lane = t & 63;
  const int w = t >> 6;  // 0..15
  __shared__ int wsum[16];
  __shared__ int carry_s;
  int carry = 0;
  for (int base = 0; base < n; base += 4096) {
    int idx = base + t * 4;
    int4 v = make_int4(0, 0, 0, 0);
    if (idx < n) v = *(const int4*)(deg + idx);
    int tsum = v.x + v.y + v.z + v.w;
    int s = tsum;
#pragma unroll
    for (int d = 1; d < 64; d <<= 1) {
      int u = __shfl_up(s, d, 64);
      if (lane >= d) s += u;
    }
    if (lane == 63) wsum[w] = s;
    __syncthreads();
    int woff = 0;
    for (int i = 0; i < w; i++) woff += wsum[i];
    int excl = carry + woff + (s - tsum);
    if (idx < n) {
      int4 o;
      o.x = excl; o.y = excl + v.x; o.z = o.y + v.y; o.w = o.z + v.z;
      *(int4*)(offs + idx) = o;
      *(int4*)(cursor + idx) = o;
    }
    __syncthreads();
    if (t == 0) {
      int tot = carry;
#pragma unroll
      for (int i = 0; i < 16; i++) tot += wsum[i];
      carry_s = tot;
    }
    __syncthreads();
    carry = carry_s;
  }
  if (t == 0) offs[n] = carry;
}

// ---------------- fill CSR bins ----------------
__global__ void k_fill(const int* __restrict__ src, const int* __restrict__ dst,
                       int* __restrict__ cursor, int* __restrict__ bins) {
  int e = blockIdx.x * 256 + threadIdx.x;
  if (e < N_EDGES) {
    int d = dst[e];
    int p = atomicAdd(&cursor[d], 1);
    bins[p] = src[e];
  }
}

// ---------------- gather means: 1 wave/node, 2 edges in flight (half-waves), 16B loads --------
__global__ void k_gather(const int* __restrict__ offs, const int* __restrict__ bins,
                         __bf16* __restrict__ Z) {
  int wid = (blockIdx.x * 256 + threadIdx.x) >> 6;
  int lane = threadIdx.x & 63;
  if (wid >= NPAD) return;
  __bf16* zrow = Z + (size_t)wid * KDIM;
  if (wid >= N_NODES) {  // zero pad rows (1024 B, 64 lanes x 16B)
    ((uint4*)zrow)[lane] = make_uint4(0, 0, 0, 0);
    return;
  }
  const int half = lane >> 5;
  const int li = lane & 31;
  const int srcoff = li * 8;  // self cols li*8..li*8+7 (x for li<16, h for li>=16)
  int beg = offs[wid], end = offs[wid + 1];
  float a[8] = {0.f, 0.f, 0.f, 0.f, 0.f, 0.f, 0.f, 0.f};
  for (int j = beg + half; j < end; j += 2) {
    int s = bins[j];
    bf16x8 v = *(const bf16x8*)(Z + (size_t)s * KDIM + srcoff);
#pragma unroll
    for (int e = 0; e < 8; ++e) a[e] += (float)v[e];
  }
#pragma unroll
  for (int e = 0; e < 8; ++e) a[e] += __shfl_xor(a[e], 32, 64);
  int degn = end - beg;
  float inv = 1.0f / (float)(degn > 0 ? degn : 1);
  if (lane < 32) {
    bf16x8 bb;
#pragma unroll
    for (int e = 0; e < 8; ++e) bb[e] = (__bf16)(a[e] * inv);
    *(bf16x8*)(zrow + 256 + srcoff) = bb;  // mean col = self col + 256
  }
}

// ---------------- fused GEMM (Z[NPAD,512] @ W^T) + LSTM epilogue, 2-phase pipelined ----------
__global__ __launch_bounds__(512) void k_gemm(
    const __bf16* __restrict__ Z, const __bf16* __restrict__ W,
    const float* __restrict__ c,
    const float* __restrict__ w_ci, const float* __restrict__ w_cf, const float* __restrict__ w_co,
    const float* __restrict__ b_i, const float* __restrict__ b_f, const float* __restrict__ b_c,
    const float* __restrict__ b_o,
    float* __restrict__ out_h, float* __restrict__ out_c) {
  __shared__ __align__(16) __bf16 As[2][64 * 32];   // [row][k], XOR-4 swizzled
  __shared__ __align__(16) __bf16 Bs[2][512 * 32];  // [n][k],   XOR-4 swizzled
  const int t = threadIdx.x;
  const int lane = t & 63;
  const int w = t >> 6;
  const int m0 = blockIdx.x * 64;
  const int l15 = lane & 15;
  const int q = lane >> 4;  // 0..3

  f32x4 acc[4][4];
#pragma unroll
  for (int m = 0; m < 4; ++m)
#pragma unroll
    for (int g = 0; g < 4; ++g) acc[m][g] = (f32x4){0.f, 0.f, 0.f, 0.f};

  const int arow = t >> 2, aslot = t & 3;
  const __bf16* aSrc = Z + (size_t)(m0 + arow) * KDIM + ((aslot ^ (arow & 3)) << 3);
  const __bf16* bSrc[4];
#pragma unroll
  for (int j = 0; j < 4; ++j) {
    int line = j * 512 + t;
    int brow = line >> 2, bslot = line & 3;
    bSrc[j] = W + (size_t)brow * KDIM + ((bslot ^ (brow & 3)) << 3);
  }

  auto STAGE = [&](int buf, int k0) {
    if (t < 256) gload_lds16(aSrc + k0, (__bf16*)As[buf] + t * 8);
#pragma unroll
    for (int j = 0; j < 4; ++j)
      gload_lds16(bSrc[j] + k0, (__bf16*)Bs[buf] + (j * 512 + t) * 8);
  };

  auto COMPUTE = [&](int buf) {
    bf16x8 af[4], bfr[4];
#pragma unroll
    for (int m = 0; m < 4; ++m) {
      int row = m * 16 + l15;
      af[m] = *(const bf16x8*)(As[buf] + row * 32 + ((q ^ (row & 3)) << 3));
    }
#pragma unroll
    for (int g = 0; g < 4; ++g) {
      int n = g * 128 + w * 16 + l15;
      bfr[g] = *(const bf16x8*)(Bs[buf] + n * 32 + ((q ^ (n & 3)) << 3));
    }
#pragma unroll
    for (int m = 0; m < 4; ++m)
#pragma unroll
      for (int g = 0; g < 4; ++g)
        acc[m][g] = __builtin_amdgcn_mfma_f32_16x16x32_bf16(af[m], bfr[g], acc[m][g], 0, 0, 0);
  };

  // 2-phase pipeline: issue next stage BEFORE computing current; one sync per K-step.
  STAGE(0, 0);
  __syncthreads();
  for (int kk = 0; kk < 8; ++kk) {
    STAGE(1, (2 * kk + 1) * 32);
    COMPUTE(0);
    __syncthreads();
    if (kk < 7) STAGE(0, (2 * kk + 2) * 32);
    COMPUTE(1);
    __syncthreads();
  }

  // epilogue: LSTM cell math, fused
  const int o = w * 16 + l15;
  const float wci = w_ci[o], wcf = w_cf[o], wco = w_co[o];
  const float bi = b_i[o], bfv = b_f[o], bc = b_c[o], bo = b_o[o];
#pragma unroll
  for (int m = 0; m < 4; ++m) {
#pragma unroll
    for (int r = 0; r < 4; ++r) {
      int row = m0 + m * 16 + q * 4 + r;
      if (row < N_NODES) {
        float cv = c[(size_t)row * D + o];
        float ig = sigm(acc[m][0][r] + wci * cv + bi);
        float fg = sigm(acc[m][1][r] + wcf * cv + bfv);
        float ct = tanh_fast(acc[m][2][r] + bc);
        float nc = fg * cv + ig * ct;
        float og = sigm(acc[m][3][r] + wco * nc + bo);
        out_h[(size_t)row * D + o] = og * tanh_fast(nc);
        out_c[(size_t)row * D + o] = nc;
      }
    }
  }
}

extern "C" void kernel_launch(void* const* d_in, const int* in_sizes, int n_in,
                              void* d_out, int out_size, void* d_ws, size_t ws_size,
                              hipStream_t stream) {
  const float* x = (const float*)d_in[0];
  const float* h = (const float*)d_in[1];
  const float* c = (const float*)d_in[2];
  const float* Wx_self = (const float*)d_in[3];
  const float* Wx_neigh = (const float*)d_in[4];
  const float* Wh_self = (const float*)d_in[5];
  const float* Wh_neigh = (const float*)d_in[6];
  const float* w_ci = (const float*)d_in[7];
  const float* w_cf = (const float*)d_in[8];
  const float* w_co = (const float*)d_in[9];
  const float* b_i = (const float*)d_in[10];
  const float* b_f = (const float*)d_in[11];
  const float* b_c = (const float*)d_in[12];
  const float* b_o = (const float*)d_in[13];
  const int* src = (const int*)d_in[14];
  const int* dst = (const int*)d_in[15];

  char* ws = (char*)d_ws;
  int* deg = (int*)(ws);                    // 50000 ints
  int* offs = (int*)(ws + 200704);          // 50001 ints
  int* cursor = (int*)(ws + 400896);        // 50000 ints
  int* bins = (int*)(ws + 601088);          // 800000 ints
  __bf16* Z = (__bf16*)(ws + 4194304);      // [50048][512] bf16 = 51.25 MB
  __bf16* W = (__bf16*)(ws + 55443456);     // [512][512] bf16

  float* out_h = (float*)d_out;
  float* out_c = out_h + (size_t)N_NODES * D;

  hipMemsetAsync(deg, 0, N_NODES * sizeof(int), stream);
  k_pre<<<NB_DEG + NB_TOB + NB_PKW, 256, 0, stream>>>(dst, deg, x, h, Z,
                                                      Wx_self, Wx_neigh, Wh_self, Wh_neigh, W);
  k_scan<<<1, 1024, 0, stream>>>(deg, offs, cursor, N_NODES);
  k_fill<<<(N_EDGES + 255) / 256, 256, 0, stream>>>(src, dst, cursor, bins);
  k_gather<<<NPAD / 4, 256, 0, stream>>>(offs, bins, Z);
  k_gemm<<<NPAD / 64, 512, 0, stream>>>(Z, W, c, w_ci, w_cf, w_co,
                                        b_i, b_f, b_c, b_o, out_h, out_c);
}

// Round 4
// 242.200 us; speedup vs baseline: 1.3760x; 1.1067x over previous
//
#include <hip/hip_runtime.h>
#include <hip/hip_bf16.h>
#include <stdint.h>

#define N_NODES 50000
#define N_EDGES 800000
#define D 128
#define NPAD 50048
#define HKD 256   // half-K: XH and ZM each have 256 cols
#define KDIM 512

typedef __attribute__((ext_vector_type(8))) __bf16 bf16x8;
typedef __attribute__((ext_vector_type(4))) __bf16 bf16x4;
typedef __attribute__((ext_vector_type(4))) float f32x4;

__device__ __forceinline__ void gload_lds16(const void* g, void* l) {
  __builtin_amdgcn_global_load_lds(
      (const __attribute__((address_space(1))) unsigned int*)(uintptr_t)g,
      (__attribute__((address_space(3))) unsigned int*)(uint32_t)(uintptr_t)l,
      16, 0, 0);
}

__device__ __forceinline__ float sigm(float v) { return 1.0f / (1.0f + __expf(-v)); }
__device__ __forceinline__ float tanh_fast(float v) { return 1.0f - 2.0f / (1.0f + __expf(2.0f * v)); }

// swizzle: chunk permutation within a 32-k row window; involution, 2-way-max banks
__device__ __forceinline__ int swz(int r) { return (r & 3) ^ ((r >> 2) & 3); }

// ---------------- merged prep: deg count + fp32->bf16 XH + weight pack ----------------
// XH row: [ x(0-127) | h(128-255) ]   (compact gather source)
// W[n=g*128+o][k]: k<128 Wx_self, <256 Wh_self, <384 Wx_neigh, else Wh_neigh
#define NB_DEG 3125   // 800000/256
#define NB_TOB 6250   // 1600000/256
#define NB_PKW 1024   // 262144/256
__global__ void k_pre(const int* __restrict__ dst, int* __restrict__ deg,
                      const float* __restrict__ x, const float* __restrict__ h,
                      __bf16* __restrict__ XH,
                      const float* __restrict__ Wx_self, const float* __restrict__ Wx_neigh,
                      const float* __restrict__ Wh_self, const float* __restrict__ Wh_neigh,
                      __bf16* __restrict__ W) {
  int b = blockIdx.x;
  if (b < NB_DEG) {
    int e = b * 256 + threadIdx.x;
    atomicAdd(&deg[dst[e]], 1);  // grid exact: 3125*256 == 800000
  } else if (b < NB_DEG + NB_TOB) {
    int idx = (b - NB_DEG) * 256 + threadIdx.x;  // 1.6M threads, 4 feats each
    int node = idx >> 5;
    int f4 = (idx & 31) << 2;
    float4 xv = *(const float4*)(x + (size_t)node * D + f4);
    float4 hv = *(const float4*)(h + (size_t)node * D + f4);
    bf16x4 a, bb;
    a[0] = (__bf16)xv.x; a[1] = (__bf16)xv.y; a[2] = (__bf16)xv.z; a[3] = (__bf16)xv.w;
    bb[0] = (__bf16)hv.x; bb[1] = (__bf16)hv.y; bb[2] = (__bf16)hv.z; bb[3] = (__bf16)hv.w;
    __bf16* xhrow = XH + (size_t)node * HKD;
    *(bf16x4*)(xhrow + f4) = a;
    *(bf16x4*)(xhrow + 128 + f4) = bb;
  } else {
    int idx = (b - NB_DEG - NB_TOB) * 256 + threadIdx.x;  // 512*512
    int nq = idx >> 9, k = idx & 511;
    int g = nq >> 7, o = nq & 127;
    const float* s; int i;
    if (k < 128)      { s = Wx_self;  i = k; }
    else if (k < 256) { s = Wh_self;  i = k - 128; }
    else if (k < 384) { s = Wx_neigh; i = k - 256; }
    else              { s = Wh_neigh; i = k - 384; }
    W[idx] = (__bf16)s[(g << 14) + (i << 7) + o];
  }
}

// ---------------- single-block exclusive scan (50000 ints, 1024 thr) ----------------
__global__ __launch_bounds__(1024) void k_scan(const int* __restrict__ deg, int* __restrict__ offs,
                                               int* __restrict__ cursor, int n) {
  const int t = threadIdx.x;
  const int lane = t & 63;
  const int w = t >> 6;  // 0..15
  __shared__ int wsum[16];
  __shared__ int carry_s;
  int carry = 0;
  for (int base = 0; base < n; base += 4096) {
    int idx = base + t * 4;
    int4 v = make_int4(0, 0, 0, 0);
    if (idx < n) v = *(const int4*)(deg + idx);
    int tsum = v.x + v.y + v.z + v.w;
    int s = tsum;
#pragma unroll
    for (int d = 1; d < 64; d <<= 1) {
      int u = __shfl_up(s, d, 64);
      if (lane >= d) s += u;
    }
    if (lane == 63) wsum[w] = s;
    __syncthreads();
    int woff = 0;
    for (int i = 0; i < w; i++) woff += wsum[i];
    int excl = carry + woff + (s - tsum);
    if (idx < n) {
      int4 o;
      o.x = excl; o.y = excl + v.x; o.z = o.y + v.y; o.w = o.z + v.z;
      *(int4*)(offs + idx) = o;
      *(int4*)(cursor + idx) = o;
    }
    __syncthreads();
    if (t == 0) {
      int tot = carry;
#pragma unroll
      for (int i = 0; i < 16; i++) tot += wsum[i];
      carry_s = tot;
    }
    __syncthreads();
    carry = carry_s;
  }
  if (t == 0) offs[n] = carry;
}

// ---------------- fill CSR bins ----------------
__global__ void k_fill(const int* __restrict__ src, const int* __restrict__ dst,
                       int* __restrict__ cursor, int* __restrict__ bins) {
  int e = blockIdx.x * 256 + threadIdx.x;
  if (e < N_EDGES) {
    int d = dst[e];
    int p = atomicAdd(&cursor[d], 1);
    bins[p] = src[e];
  }
}

// ---------------- gather means: 1 wave/node, 2 edges in flight (half-waves), 16B loads --------
// reads compact XH rows (512 B), writes ZM row: [ mean_x(0-127) | mean_h(128-255) ]
__global__ void k_gather(const int* __restrict__ offs, const int* __restrict__ bins,
                         const __bf16* __restrict__ XH, __bf16* __restrict__ ZM) {
  int wid = (blockIdx.x * 256 + threadIdx.x) >> 6;
  int lane = threadIdx.x & 63;
  if (wid >= NPAD) return;
  if (wid >= N_NODES) {  // zero pad rows of both XH and ZM (512 B each, 64 lanes x 8B)
    ((uint2*)(XH + (size_t)wid * HKD))[lane] = make_uint2(0, 0);
    ((uint2*)(ZM + (size_t)wid * HKD))[lane] = make_uint2(0, 0);
    return;
  }
  const int half = lane >> 5;
  const int li = lane & 31;
  const int srcoff = li * 8;  // cols li*8..li*8+7 of the 256-col XH row
  int beg = offs[wid], end = offs[wid + 1];
  float a[8] = {0.f, 0.f, 0.f, 0.f, 0.f, 0.f, 0.f, 0.f};
  for (int j = beg + half; j < end; j += 2) {
    int s = bins[j];
    bf16x8 v = *(const bf16x8*)(XH + (size_t)s * HKD + srcoff);
#pragma unroll
    for (int e = 0; e < 8; ++e) a[e] += (float)v[e];
  }
#pragma unroll
  for (int e = 0; e < 8; ++e) a[e] += __shfl_xor(a[e], 32, 64);
  int degn = end - beg;
  float inv = 1.0f / (float)(degn > 0 ? degn : 1);
  if (lane < 32) {
    bf16x8 bb;
#pragma unroll
    for (int e = 0; e < 8; ++e) bb[e] = (__bf16)(a[e] * inv);
    *(bf16x8*)(ZM + (size_t)wid * HKD + srcoff) = bb;
  }
}

// ---------------- fused GEMM + LSTM epilogue ----------------
// 256 threads / 4 waves, BM=64, BN=256 (one o-half x 4 gates), BK=32, single-buffered 20KB LDS.
// A cols: k<256 from XH, k>=256 from ZM. Wave w owns o = o0 + w*16 + l15; frag g = gate g.
__global__ __launch_bounds__(256, 4) void k_gemm(
    const __bf16* __restrict__ XH, const __bf16* __restrict__ ZM, const __bf16* __restrict__ W,
    const float* __restrict__ c,
    const float* __restrict__ w_ci, const float* __restrict__ w_cf, const float* __restrict__ w_co,
    const float* __restrict__ b_i, const float* __restrict__ b_f, const float* __restrict__ b_c,
    const float* __restrict__ b_o,
    float* __restrict__ out_h, float* __restrict__ out_c) {
  __shared__ __align__(16) __bf16 As[64 * 32];    // [row][k-chunk swizzled]
  __shared__ __align__(16) __bf16 Bs[256 * 32];   // [n_local][k-chunk swizzled]
  const int t = threadIdx.x;
  const int lane = t & 63;
  const int w = t >> 6;  // 0..3
  const int m0 = (blockIdx.x >> 1) * 64;
  const int o0 = (blockIdx.x & 1) * 64;
  const int l15 = lane & 15;
  const int q = lane >> 4;  // 0..3

  f32x4 acc[4][4];
#pragma unroll
  for (int m = 0; m < 4; ++m)
#pragma unroll
    for (int g = 0; g < 4; ++g) acc[m][g] = (f32x4){0.f, 0.f, 0.f, 0.f};

  // A staging: row=t>>2, chunk=t&3; source chunk pre-swizzled
  const int arow = t >> 2, aslot = t & 3;
  const size_t aoff = (size_t)(m0 + arow) * HKD + ((aslot ^ swz(arow)) << 3);
  // B staging: 4 lines per thread; local n row = (l>>2), W row = gate*128 + o0 + (n&63)
  const __bf16* bSrc[4];
#pragma unroll
  for (int j = 0; j < 4; ++j) {
    int l = j * 256 + t;
    int brow = l >> 2, bslot = l & 3;
    int wrow = (brow >> 6) * 128 + o0 + (brow & 63);
    bSrc[j] = W + (size_t)wrow * KDIM + ((bslot ^ swz(brow)) << 3);
  }

  for (int k0 = 0; k0 < KDIM; k0 += 32) {
    const __bf16* sA = (k0 < 256) ? (XH + aoff + k0) : (ZM + aoff + (k0 - 256));
    gload_lds16(sA, (__bf16*)As + t * 8);
#pragma unroll
    for (int j = 0; j < 4; ++j)
      gload_lds16(bSrc[j] + k0, (__bf16*)Bs + (j * 256 + t) * 8);
    __syncthreads();  // compiler drains vmcnt before barrier

    bf16x8 af[4], bfr[4];
#pragma unroll
    for (int m = 0; m < 4; ++m) {
      int row = m * 16 + l15;
      af[m] = *(const bf16x8*)(As + row * 32 + ((q ^ swz(row)) << 3));
    }
#pragma unroll
    for (int g = 0; g < 4; ++g) {
      int n = g * 64 + w * 16 + l15;
      bfr[g] = *(const bf16x8*)(Bs + n * 32 + ((q ^ swz(n)) << 3));
    }
#pragma unroll
    for (int m = 0; m < 4; ++m)
#pragma unroll
      for (int g = 0; g < 4; ++g)
        acc[m][g] = __builtin_amdgcn_mfma_f32_16x16x32_bf16(af[m], bfr[g], acc[m][g], 0, 0, 0);
    __syncthreads();
  }

  // epilogue: LSTM cell math, fused
  const int o = o0 + w * 16 + l15;
  const float wci = w_ci[o], wcf = w_cf[o], wco = w_co[o];
  const float bi = b_i[o], bfv = b_f[o], bc = b_c[o], bo = b_o[o];
#pragma unroll
  for (int m = 0; m < 4; ++m) {
#pragma unroll
    for (int r = 0; r < 4; ++r) {
      int row = m0 + m * 16 + q * 4 + r;
      if (row < N_NODES) {
        float cv = c[(size_t)row * D + o];
        float ig = sigm(acc[m][0][r] + wci * cv + bi);
        float fg = sigm(acc[m][1][r] + wcf * cv + bfv);
        float ct = tanh_fast(acc[m][2][r] + bc);
        float nc = fg * cv + ig * ct;
        float og = sigm(acc[m][3][r] + wco * nc + bo);
        out_h[(size_t)row * D + o] = og * tanh_fast(nc);
        out_c[(size_t)row * D + o] = nc;
      }
    }
  }
}

extern "C" void kernel_launch(void* const* d_in, const int* in_sizes, int n_in,
                              void* d_out, int out_size, void* d_ws, size_t ws_size,
                              hipStream_t stream) {
  const float* x = (const float*)d_in[0];
  const float* h = (const float*)d_in[1];
  const float* c = (const float*)d_in[2];
  const float* Wx_self = (const float*)d_in[3];
  const float* Wx_neigh = (const float*)d_in[4];
  const float* Wh_self = (const float*)d_in[5];
  const float* Wh_neigh = (const float*)d_in[6];
  const float* w_ci = (const float*)d_in[7];
  const float* w_cf = (const float*)d_in[8];
  const float* w_co = (const float*)d_in[9];
  const float* b_i = (const float*)d_in[10];
  const float* b_f = (const float*)d_in[11];
  const float* b_c = (const float*)d_in[12];
  const float* b_o = (const float*)d_in[13];
  const int* src = (const int*)d_in[14];
  const int* dst = (const int*)d_in[15];

  char* ws = (char*)d_ws;
  int* deg = (int*)(ws);                    // 50000 ints
  int* offs = (int*)(ws + 200704);          // 50001 ints
  int* cursor = (int*)(ws + 400896);        // 50000 ints
  int* bins = (int*)(ws + 601088);          // 800000 ints
  __bf16* XH = (__bf16*)(ws + 4194304);     // [50048][256] bf16 = 25.6 MB
  __bf16* ZM = (__bf16*)(ws + 29818880);    // [50048][256] bf16 = 25.6 MB
  __bf16* W = (__bf16*)(ws + 55443456);     // [512][512] bf16

  float* out_h = (float*)d_out;
  float* out_c = out_h + (size_t)N_NODES * D;

  hipMemsetAsync(deg, 0, N_NODES * sizeof(int), stream);
  k_pre<<<NB_DEG + NB_TOB + NB_PKW, 256, 0, stream>>>(dst, deg, x, h, XH,
                                                      Wx_self, Wx_neigh, Wh_self, Wh_neigh, W);
  k_scan<<<1, 1024, 0, stream>>>(deg, offs, cursor, N_NODES);
  k_fill<<<(N_EDGES + 255) / 256, 256, 0, stream>>>(src, dst, cursor, bins);
  k_gather<<<NPAD / 4, 256, 0, stream>>>(offs, bins, XH, ZM);
  k_gemm<<<(NPAD / 64) * 2, 256, 0, stream>>>(XH, ZM, W, c, w_ci, w_cf, w_co,
                                              b_i, b_f, b_c, b_o, out_h, out_c);
}

// Round 5
// 241.283 us; speedup vs baseline: 1.3812x; 1.0038x over previous
//
#include <hip/hip_runtime.h>
#include <hip/hip_bf16.h>
#include <stdint.h>

#define N_NODES 50000
#define N_EDGES 800000
#define D 128
#define NPAD 50048
#define HKD 256   // half-K: XH and ZM each have 256 cols
#define KDIM 512

typedef __attribute__((ext_vector_type(8))) __bf16 bf16x8;
typedef __attribute__((ext_vector_type(4))) __bf16 bf16x4;
typedef __attribute__((ext_vector_type(4))) float f32x4;

__device__ __forceinline__ void gload_lds16(const void* g, void* l) {
  __builtin_amdgcn_global_load_lds(
      (const __attribute__((address_space(1))) unsigned int*)(uintptr_t)g,
      (__attribute__((address_space(3))) unsigned int*)(uint32_t)(uintptr_t)l,
      16, 0, 0);
}

__device__ __forceinline__ float sigm(float v) { return 1.0f / (1.0f + __expf(-v)); }
__device__ __forceinline__ float tanh_fast(float v) { return 1.0f - 2.0f / (1.0f + __expf(2.0f * v)); }

// swizzle: chunk permutation within a 32-k row window; involution, bounded banks
__device__ __forceinline__ int swz(int r) { return (r & 3) ^ ((r >> 2) & 3); }

// ---------------- merged prep: deg count + fp32->bf16 XH + weight pack ----------------
// XH row: [ x(0-127) | h(128-255) ]   (compact gather source)
// W[n=g*128+o][k]: k<128 Wx_self, <256 Wh_self, <384 Wx_neigh, else Wh_neigh
#define NB_DEG 3125   // 800000/256
#define NB_TOB 6250   // 1600000/256
#define NB_PKW 1024   // 262144/256
__global__ void k_pre(const int* __restrict__ dst, int* __restrict__ deg,
                      const float* __restrict__ x, const float* __restrict__ h,
                      __bf16* __restrict__ XH,
                      const float* __restrict__ Wx_self, const float* __restrict__ Wx_neigh,
                      const float* __restrict__ Wh_self, const float* __restrict__ Wh_neigh,
                      __bf16* __restrict__ W) {
  int b = blockIdx.x;
  if (b < NB_DEG) {
    int e = b * 256 + threadIdx.x;
    atomicAdd(&deg[dst[e]], 1);  // grid exact: 3125*256 == 800000
  } else if (b < NB_DEG + NB_TOB) {
    int idx = (b - NB_DEG) * 256 + threadIdx.x;  // 1.6M threads, 4 feats each
    int node = idx >> 5;
    int f4 = (idx & 31) << 2;
    float4 xv = *(const float4*)(x + (size_t)node * D + f4);
    float4 hv = *(const float4*)(h + (size_t)node * D + f4);
    bf16x4 a, bb;
    a[0] = (__bf16)xv.x; a[1] = (__bf16)xv.y; a[2] = (__bf16)xv.z; a[3] = (__bf16)xv.w;
    bb[0] = (__bf16)hv.x; bb[1] = (__bf16)hv.y; bb[2] = (__bf16)hv.z; bb[3] = (__bf16)hv.w;
    __bf16* xhrow = XH + (size_t)node * HKD;
    *(bf16x4*)(xhrow + f4) = a;
    *(bf16x4*)(xhrow + 128 + f4) = bb;
  } else {
    int idx = (b - NB_DEG - NB_TOB) * 256 + threadIdx.x;  // 512*512
    int nq = idx >> 9, k = idx & 511;
    int g = nq >> 7, o = nq & 127;
    const float* s; int i;
    if (k < 128)      { s = Wx_self;  i = k; }
    else if (k < 256) { s = Wh_self;  i = k - 128; }
    else if (k < 384) { s = Wx_neigh; i = k - 256; }
    else              { s = Wh_neigh; i = k - 384; }
    W[idx] = (__bf16)s[(g << 14) + (i << 7) + o];
  }
}

// ---------------- single-block exclusive scan (50000 ints, 1024 thr) ----------------
__global__ __launch_bounds__(1024) void k_scan(const int* __restrict__ deg, int* __restrict__ offs,
                                               int* __restrict__ cursor, int n) {
  const int t = threadIdx.x;
  const int lane = t & 63;
  const int w = t >> 6;  // 0..15
  __shared__ int wsum[16];
  __shared__ int carry_s;
  int carry = 0;
  for (int base = 0; base < n; base += 4096) {
    int idx = base + t * 4;
    int4 v = make_int4(0, 0, 0, 0);
    if (idx < n) v = *(const int4*)(deg + idx);
    int tsum = v.x + v.y + v.z + v.w;
    int s = tsum;
#pragma unroll
    for (int d = 1; d < 64; d <<= 1) {
      int u = __shfl_up(s, d, 64);
      if (lane >= d) s += u;
    }
    if (lane == 63) wsum[w] = s;
    __syncthreads();
    int woff = 0;
    for (int i = 0; i < w; i++) woff += wsum[i];
    int excl = carry + woff + (s - tsum);
    if (idx < n) {
      int4 o;
      o.x = excl; o.y = excl + v.x; o.z = o.y + v.y; o.w = o.z + v.z;
      *(int4*)(offs + idx) = o;
      *(int4*)(cursor + idx) = o;
    }
    __syncthreads();
    if (t == 0) {
      int tot = carry;
#pragma unroll
      for (int i = 0; i < 16; i++) tot += wsum[i];
      carry_s = tot;
    }
    __syncthreads();
    carry = carry_s;
  }
  if (t == 0) offs[n] = carry;
}

// ---------------- fill CSR bins ----------------
__global__ void k_fill(const int* __restrict__ src, const int* __restrict__ dst,
                       int* __restrict__ cursor, int* __restrict__ bins) {
  int e = blockIdx.x * 256 + threadIdx.x;
  if (e < N_EDGES) {
    int d = dst[e];
    int p = atomicAdd(&cursor[d], 1);
    bins[p] = src[e];
  }
}

// ---------------- gather means: 1 wave/node, 2 edges in flight (half-waves), 16B loads --------
// reads compact XH rows (512 B), writes ZM row: [ mean_x(0-127) | mean_h(128-255) ]
__global__ void k_gather(const int* __restrict__ offs, const int* __restrict__ bins,
                         const __bf16* __restrict__ XH, __bf16* __restrict__ ZM) {
  int wid = (blockIdx.x * 256 + threadIdx.x) >> 6;
  int lane = threadIdx.x & 63;
  if (wid >= NPAD) return;
  if (wid >= N_NODES) {  // zero pad rows of both XH and ZM (512 B each, 64 lanes x 8B)
    ((uint2*)(XH + (size_t)wid * HKD))[lane] = make_uint2(0, 0);
    ((uint2*)(ZM + (size_t)wid * HKD))[lane] = make_uint2(0, 0);
    return;
  }
  const int half = lane >> 5;
  const int li = lane & 31;
  const int srcoff = li * 8;  // cols li*8..li*8+7 of the 256-col XH row
  int beg = offs[wid], end = offs[wid + 1];
  float a[8] = {0.f, 0.f, 0.f, 0.f, 0.f, 0.f, 0.f, 0.f};
  for (int j = beg + half; j < end; j += 2) {
    int s = bins[j];
    bf16x8 v = *(const bf16x8*)(XH + (size_t)s * HKD + srcoff);
#pragma unroll
    for (int e = 0; e < 8; ++e) a[e] += (float)v[e];
  }
#pragma unroll
  for (int e = 0; e < 8; ++e) a[e] += __shfl_xor(a[e], 32, 64);
  int degn = end - beg;
  float inv = 1.0f / (float)(degn > 0 ? degn : 1);
  if (lane < 32) {
    bf16x8 bb;
#pragma unroll
    for (int e = 0; e < 8; ++e) bb[e] = (__bf16)(a[e] * inv);
    *(bf16x8*)(ZM + (size_t)wid * HKD + srcoff) = bb;
  }
}

// ---------------- fused GEMM + LSTM epilogue, 2-deep counted-vmcnt pipeline ----------------
// 256 threads / 4 waves, BM=64, BN=256 (one o-half x 4 gates), BK=32, dbuf 40KB LDS.
// Per K-step each thread issues 5 gload_lds (1 A + 4 B). Next step's 5 stay in flight:
// wait vmcnt(5) (current buffer's stores landed), raw s_barrier, ds_read+MFMA, s_barrier.
__global__ __launch_bounds__(256, 4) void k_gemm(
    const __bf16* __restrict__ XH, const __bf16* __restrict__ ZM, const __bf16* __restrict__ W,
    const float* __restrict__ c,
    const float* __restrict__ w_ci, const float* __restrict__ w_cf, const float* __restrict__ w_co,
    const float* __restrict__ b_i, const float* __restrict__ b_f, const float* __restrict__ b_c,
    const float* __restrict__ b_o,
    float* __restrict__ out_h, float* __restrict__ out_c) {
  __shared__ __align__(16) __bf16 As[2][64 * 32];    // 8 KB
  __shared__ __align__(16) __bf16 Bs[2][256 * 32];   // 32 KB
  const int t = threadIdx.x;
  const int lane = t & 63;
  const int w = t >> 6;  // 0..3
  const int m0 = (blockIdx.x >> 1) * 64;
  const int o0 = (blockIdx.x & 1) * 64;
  const int l15 = lane & 15;
  const int q = lane >> 4;  // 0..3

  f32x4 acc[4][4];
#pragma unroll
  for (int m = 0; m < 4; ++m)
#pragma unroll
    for (int g = 0; g < 4; ++g) acc[m][g] = (f32x4){0.f, 0.f, 0.f, 0.f};

  // A staging: row=t>>2, chunk=t&3; source chunk pre-swizzled. k<256 from XH, else ZM.
  const int arow = t >> 2, aslot = t & 3;
  const size_t aoff = (size_t)(m0 + arow) * HKD + ((aslot ^ swz(arow)) << 3);
  // B staging: 4 lines per thread
  const __bf16* bSrc[4];
#pragma unroll
  for (int j = 0; j < 4; ++j) {
    int l = j * 256 + t;
    int brow = l >> 2, bslot = l & 3;
    int wrow = (brow >> 6) * 128 + o0 + (brow & 63);
    bSrc[j] = W + (size_t)wrow * KDIM + ((bslot ^ swz(brow)) << 3);
  }

  auto STAGE = [&](int buf, int k0) {
    const __bf16* sA = (k0 < 256) ? (XH + aoff + k0) : (ZM + aoff + (k0 - 256));
    gload_lds16(sA, &As[buf][t * 8]);
#pragma unroll
    for (int j = 0; j < 4; ++j)
      gload_lds16(bSrc[j] + k0, &Bs[buf][(j * 256 + t) * 8]);
  };

  auto COMPUTE = [&](int buf) {
    bf16x8 af[4], bfr[4];
#pragma unroll
    for (int m = 0; m < 4; ++m) {
      int row = m * 16 + l15;
      af[m] = *(const bf16x8*)(&As[buf][row * 32 + ((q ^ swz(row)) << 3)]);
    }
#pragma unroll
    for (int g = 0; g < 4; ++g) {
      int n = g * 64 + w * 16 + l15;
      bfr[g] = *(const bf16x8*)(&Bs[buf][n * 32 + ((q ^ swz(n)) << 3)]);
    }
#pragma unroll
    for (int m = 0; m < 4; ++m)
#pragma unroll
      for (int g = 0; g < 4; ++g)
        acc[m][g] = __builtin_amdgcn_mfma_f32_16x16x32_bf16(af[m], bfr[g], acc[m][g], 0, 0, 0);
  };

  // prologue
  STAGE(0, 0);
  __builtin_amdgcn_sched_barrier(0);
  // main: 7 full pairs (kk = 0..13)
  for (int kk2 = 0; kk2 < 7; ++kk2) {
    STAGE(1, 64 * kk2 + 32);
    asm volatile("s_waitcnt vmcnt(5)" ::: "memory");
    __builtin_amdgcn_s_barrier();
    __builtin_amdgcn_sched_barrier(0);
    COMPUTE(0);
    __builtin_amdgcn_sched_barrier(0);
    __builtin_amdgcn_s_barrier();

    STAGE(0, 64 * kk2 + 64);
    asm volatile("s_waitcnt vmcnt(5)" ::: "memory");
    __builtin_amdgcn_s_barrier();
    __builtin_amdgcn_sched_barrier(0);
    COMPUTE(1);
    __builtin_amdgcn_sched_barrier(0);
    __builtin_amdgcn_s_barrier();
  }
  // kk = 14: compute buf0 @448, stage buf1 @480
  STAGE(1, 480);
  asm volatile("s_waitcnt vmcnt(5)" ::: "memory");
  __builtin_amdgcn_s_barrier();
  __builtin_amdgcn_sched_barrier(0);
  COMPUTE(0);
  __builtin_amdgcn_sched_barrier(0);
  __builtin_amdgcn_s_barrier();
  // kk = 15: compute buf1 @480 (drain)
  asm volatile("s_waitcnt vmcnt(0)" ::: "memory");
  __builtin_amdgcn_s_barrier();
  __builtin_amdgcn_sched_barrier(0);
  COMPUTE(1);
  __builtin_amdgcn_sched_barrier(0);

  // epilogue: LSTM cell math, fused
  const int o = o0 + w * 16 + l15;
  const float wci = w_ci[o], wcf = w_cf[o], wco = w_co[o];
  const float bi = b_i[o], bfv = b_f[o], bc = b_c[o], bo = b_o[o];
#pragma unroll
  for (int m = 0; m < 4; ++m) {
#pragma unroll
    for (int r = 0; r < 4; ++r) {
      int row = m0 + m * 16 + q * 4 + r;
      if (row < N_NODES) {
        float cv = c[(size_t)row * D + o];
        float ig = sigm(acc[m][0][r] + wci * cv + bi);
        float fg = sigm(acc[m][1][r] + wcf * cv + bfv);
        float ct = tanh_fast(acc[m][2][r] + bc);
        float nc = fg * cv + ig * ct;
        float og = sigm(acc[m][3][r] + wco * nc + bo);
        out_h[(size_t)row * D + o] = og * tanh_fast(nc);
        out_c[(size_t)row * D + o] = nc;
      }
    }
  }
}

extern "C" void kernel_launch(void* const* d_in, const int* in_sizes, int n_in,
                              void* d_out, int out_size, void* d_ws, size_t ws_size,
                              hipStream_t stream) {
  const float* x = (const float*)d_in[0];
  const float* h = (const float*)d_in[1];
  const float* c = (const float*)d_in[2];
  const float* Wx_self = (const float*)d_in[3];
  const float* Wx_neigh = (const float*)d_in[4];
  const float* Wh_self = (const float*)d_in[5];
  const float* Wh_neigh = (const float*)d_in[6];
  const float* w_ci = (const float*)d_in[7];
  const float* w_cf = (const float*)d_in[8];
  const float* w_co = (const float*)d_in[9];
  const float* b_i = (const float*)d_in[10];
  const float* b_f = (const float*)d_in[11];
  const float* b_c = (const float*)d_in[12];
  const float* b_o = (const float*)d_in[13];
  const int* src = (const int*)d_in[14];
  const int* dst = (const int*)d_in[15];

  char* ws = (char*)d_ws;
  int* deg = (int*)(ws);                    // 50000 ints
  int* offs = (int*)(ws + 200704);          // 50001 ints
  int* cursor = (int*)(ws + 400896);        // 50000 ints
  int* bins = (int*)(ws + 601088);          // 800000 ints
  __bf16* XH = (__bf16*)(ws + 4194304);     // [50048][256] bf16 = 25.6 MB
  __bf16* ZM = (__bf16*)(ws + 29818880);    // [50048][256] bf16 = 25.6 MB
  __bf16* W = (__bf16*)(ws + 55443456);     // [512][512] bf16

  float* out_h = (float*)d_out;
  float* out_c = out_h + (size_t)N_NODES * D;

  hipMemsetAsync(deg, 0, N_NODES * sizeof(int), stream);
  k_pre<<<NB_DEG + NB_TOB + NB_PKW, 256, 0, stream>>>(dst, deg, x, h, XH,
                                                      Wx_self, Wx_neigh, Wh_self, Wh_neigh, W);
  k_scan<<<1, 1024, 0, stream>>>(deg, offs, cursor, N_NODES);
  k_fill<<<(N_EDGES + 255) / 256, 256, 0, stream>>>(src, dst, cursor, bins);
  k_gather<<<NPAD / 4, 256, 0, stream>>>(offs, bins, XH, ZM);
  k_gemm<<<(NPAD / 64) * 2, 256, 0, stream>>>(XH, ZM, W, c, w_ci, w_cf, w_co,
                                              b_i, b_f, b_c, b_o, out_h, out_c);
}

// Round 6
// 229.198 us; speedup vs baseline: 1.4541x; 1.0527x over previous
//
#include <hip/hip_runtime.h>
#include <hip/hip_bf16.h>
#include <stdint.h>

#define N_NODES 50000
#define N_EDGES 800000
#define D 128
#define NPAD 50048
#define HKD 256   // half-K: XH and ZM each have 256 cols
#define KDIM 512

typedef __attribute__((ext_vector_type(8))) __bf16 bf16x8;
typedef __attribute__((ext_vector_type(4))) __bf16 bf16x4;
typedef __attribute__((ext_vector_type(4))) float f32x4;

__device__ __forceinline__ void gload_lds16(const void* g, void* l) {
  __builtin_amdgcn_global_load_lds(
      (const __attribute__((address_space(1))) unsigned int*)(uintptr_t)g,
      (__attribute__((address_space(3))) unsigned int*)(uint32_t)(uintptr_t)l,
      16, 0, 0);
}

__device__ __forceinline__ float sigm(float v) { return 1.0f / (1.0f + __expf(-v)); }
__device__ __forceinline__ float tanh_fast(float v) { return 1.0f - 2.0f / (1.0f + __expf(2.0f * v)); }

// ---------------- merged prep: deg count + fp32->bf16 XH + weight pack ----------------
// XH row: [ x(0-127) | h(128-255) ]
// Wp frag-major: idx = ((G*16 + step)*64 + q*16 + r16)*8 + e
//   where wrow = G*16 + r16 (= gate*128 + o), k = step*32 + q*8 + e
//   k<128 Wx_self, <256 Wh_self, <384 Wx_neigh, else Wh_neigh (matches XH|ZM col order)
#define NB_DEG 3125   // 800000/256
#define NB_TOB 6250   // 1600000/256
#define NB_PKW 1024   // 262144/256
__global__ void k_pre(const int* __restrict__ dst, int* __restrict__ deg,
                      const float* __restrict__ x, const float* __restrict__ h,
                      __bf16* __restrict__ XH,
                      const float* __restrict__ Wx_self, const float* __restrict__ Wx_neigh,
                      const float* __restrict__ Wh_self, const float* __restrict__ Wh_neigh,
                      __bf16* __restrict__ Wp) {
  int b = blockIdx.x;
  if (b < NB_DEG) {
    int e = b * 256 + threadIdx.x;
    atomicAdd(&deg[dst[e]], 1);  // grid exact: 3125*256 == 800000
  } else if (b < NB_DEG + NB_TOB) {
    int idx = (b - NB_DEG) * 256 + threadIdx.x;  // 1.6M threads, 4 feats each
    int node = idx >> 5;
    int f4 = (idx & 31) << 2;
    float4 xv = *(const float4*)(x + (size_t)node * D + f4);
    float4 hv = *(const float4*)(h + (size_t)node * D + f4);
    bf16x4 a, bb;
    a[0] = (__bf16)xv.x; a[1] = (__bf16)xv.y; a[2] = (__bf16)xv.z; a[3] = (__bf16)xv.w;
    bb[0] = (__bf16)hv.x; bb[1] = (__bf16)hv.y; bb[2] = (__bf16)hv.z; bb[3] = (__bf16)hv.w;
    __bf16* xhrow = XH + (size_t)node * HKD;
    *(bf16x4*)(xhrow + f4) = a;
    *(bf16x4*)(xhrow + 128 + f4) = bb;
  } else {
    int idx = (b - NB_DEG - NB_TOB) * 256 + threadIdx.x;  // 0..262143
    int e = idx & 7;
    int r16 = (idx >> 3) & 15;
    int q = (idx >> 7) & 3;
    int s = (idx >> 9) & 15;
    int G = idx >> 13;           // 0..31
    int wrow = G * 16 + r16;     // gate*128 + o
    int g = wrow >> 7, o = wrow & 127;
    int k = s * 32 + q * 8 + e;
    const float* src; int i;
    if (k < 128)      { src = Wx_self;  i = k; }
    else if (k < 256) { src = Wh_self;  i = k - 128; }
    else if (k < 384) { src = Wx_neigh; i = k - 256; }
    else              { src = Wh_neigh; i = k - 384; }
    Wp[idx] = (__bf16)src[(g << 14) + (i << 7) + o];
  }
}

// ---------------- single-block exclusive scan (50000 ints, 1024 thr) ----------------
__global__ __launch_bounds__(1024) void k_scan(const int* __restrict__ deg, int* __restrict__ offs,
                                               int* __restrict__ cursor, int n) {
  const int t = threadIdx.x;
  const int lane = t & 63;
  const int w = t >> 6;  // 0..15
  __shared__ int wsum[16];
  __shared__ int carry_s;
  int carry = 0;
  for (int base = 0; base < n; base += 4096) {
    int idx = base + t * 4;
    int4 v = make_int4(0, 0, 0, 0);
    if (idx < n) v = *(const int4*)(deg + idx);
    int tsum = v.x + v.y + v.z + v.w;
    int s = tsum;
#pragma unroll
    for (int d = 1; d < 64; d <<= 1) {
      int u = __shfl_up(s, d, 64);
      if (lane >= d) s += u;
    }
    if (lane == 63) wsum[w] = s;
    __syncthreads();
    int woff = 0;
    for (int i = 0; i < w; i++) woff += wsum[i];
    int excl = carry + woff + (s - tsum);
    if (idx < n) {
      int4 o;
      o.x = excl; o.y = excl + v.x; o.z = o.y + v.y; o.w = o.z + v.z;
      *(int4*)(offs + idx) = o;
      *(int4*)(cursor + idx) = o;
    }
    __syncthreads();
    if (t == 0) {
      int tot = carry;
#pragma unroll
      for (int i = 0; i < 16; i++) tot += wsum[i];
      carry_s = tot;
    }
    __syncthreads();
    carry = carry_s;
  }
  if (t == 0) offs[n] = carry;
}

// ---------------- fill CSR bins ----------------
__global__ void k_fill(const int* __restrict__ src, const int* __restrict__ dst,
                       int* __restrict__ cursor, int* __restrict__ bins) {
  int e = blockIdx.x * 256 + threadIdx.x;
  if (e < N_EDGES) {
    int d = dst[e];
    int p = atomicAdd(&cursor[d], 1);
    bins[p] = src[e];
  }
}

// ---------------- gather means: 1 wave/node, 4 edges in flight (2/half-wave), 16B loads ------
__global__ void k_gather(const int* __restrict__ offs, const int* __restrict__ bins,
                         const __bf16* __restrict__ XH, __bf16* __restrict__ ZM) {
  int wid = (blockIdx.x * 256 + threadIdx.x) >> 6;
  int lane = threadIdx.x & 63;
  if (wid >= NPAD) return;
  if (wid >= N_NODES) {  // zero pad rows of both XH and ZM (512 B each, 64 lanes x 8B)
    ((uint2*)(XH + (size_t)wid * HKD))[lane] = make_uint2(0, 0);
    ((uint2*)(ZM + (size_t)wid * HKD))[lane] = make_uint2(0, 0);
    return;
  }
  const int half = lane >> 5;
  const int li = lane & 31;
  const int srcoff = li * 8;
  int beg = offs[wid], end = offs[wid + 1];
  float a[8] = {0.f, 0.f, 0.f, 0.f, 0.f, 0.f, 0.f, 0.f};
  float a2[8] = {0.f, 0.f, 0.f, 0.f, 0.f, 0.f, 0.f, 0.f};
  int j = beg + half;
  for (; j + 2 < end; j += 4) {
    int s0 = bins[j];
    int s1 = bins[j + 2];
    bf16x8 v0 = *(const bf16x8*)(XH + (size_t)s0 * HKD + srcoff);
    bf16x8 v1 = *(const bf16x8*)(XH + (size_t)s1 * HKD + srcoff);
#pragma unroll
    for (int e = 0; e < 8; ++e) { a[e] += (float)v0[e]; a2[e] += (float)v1[e]; }
  }
  if (j < end) {
    int s0 = bins[j];
    bf16x8 v0 = *(const bf16x8*)(XH + (size_t)s0 * HKD + srcoff);
#pragma unroll
    for (int e = 0; e < 8; ++e) a[e] += (float)v0[e];
  }
#pragma unroll
  for (int e = 0; e < 8; ++e) {
    a[e] += a2[e];
    a[e] += __shfl_xor(a[e], 32, 64);
  }
  int degn = end - beg;
  float inv = 1.0f / (float)(degn > 0 ? degn : 1);
  if (lane < 32) {
    bf16x8 bb;
#pragma unroll
    for (int e = 0; e < 8; ++e) bb[e] = (__bf16)(a[e] * inv);
    *(bf16x8*)(ZM + (size_t)wid * HKD + srcoff) = bb;
  }
}

// ---------------- fused GEMM + LSTM epilogue: barrier-free K-loop ----------------
// 512 threads / 8 waves, BM=64, BN=512 (all o x all gates). A-tile (64KB) staged to LDS
// ONCE (swizzled), one barrier, then 16 K-steps of pure {global B-frag, ds_read A, MFMA}.
// Wave w owns o = w*16 + l15, all 4 gates (frag g). B from frag-major Wp, 1KB/frag coalesced.
__global__ __launch_bounds__(512, 4) void k_gemm(
    const __bf16* __restrict__ XH, const __bf16* __restrict__ ZM, const __bf16* __restrict__ Wp,
    const float* __restrict__ c,
    const float* __restrict__ w_ci, const float* __restrict__ w_cf, const float* __restrict__ w_co,
    const float* __restrict__ b_i, const float* __restrict__ b_f, const float* __restrict__ b_c,
    const float* __restrict__ b_o,
    float* __restrict__ out_h, float* __restrict__ out_c) {
  __shared__ __align__(16) __bf16 As[64 * KDIM];  // 64 KB, 16B chunks XOR-swizzled per row
  const int t = threadIdx.x;
  const int lane = t & 63;
  const int w = t >> 6;  // 0..7
  const int m0 = blockIdx.x * 64;
  const int l15 = lane & 15;
  const int q = lane >> 4;  // 0..3

  // ---- stage A: 8 rounds x 512 thr x 16B; LDS slot s holds global chunk (s&63)^(row&7) ----
#pragma unroll
  for (int i = 0; i < 8; ++i) {
    int s = i * 512 + t;
    int row = s >> 6;
    int cg = (s & 63) ^ (row & 7);
    const __bf16* src = (cg < 32) ? (XH + (size_t)(m0 + row) * HKD + cg * 8)
                                  : (ZM + (size_t)(m0 + row) * HKD + (cg - 32) * 8);
    gload_lds16(src, (__bf16*)As + s * 8);
  }
  __syncthreads();  // drains vmcnt; ONLY barrier in the kernel

  f32x4 acc[4][4];
#pragma unroll
  for (int m = 0; m < 4; ++m)
#pragma unroll
    for (int g = 0; g < 4; ++g) acc[m][g] = (f32x4){0.f, 0.f, 0.f, 0.f};

  // B frag base: frag g, step s -> Wp + ((g*8 + w)*16 + s)*512 + lane*8 (1KB contiguous/wave)
  const __bf16* wp = Wp + (size_t)(w * 16) * 512 + lane * 8;

  bf16x8 bA[4], bB[4];
#pragma unroll
  for (int g = 0; g < 4; ++g) bA[g] = *(const bf16x8*)(wp + g * 65536);

#pragma unroll
  for (int s2 = 0; s2 < 8; ++s2) {
    {  // even step: compute bA, prefetch bB
      const int step = 2 * s2;
#pragma unroll
      for (int g = 0; g < 4; ++g)
        bB[g] = *(const bf16x8*)(wp + g * 65536 + (step + 1) * 512);
      bf16x8 af[4];
#pragma unroll
      for (int m = 0; m < 4; ++m) {
        int row = m * 16 + l15;
        int cl = (step * 4 + q) ^ (row & 7);
        af[m] = *(const bf16x8*)(As + (row * 64 + cl) * 8);
      }
#pragma unroll
      for (int m = 0; m < 4; ++m)
#pragma unroll
        for (int g = 0; g < 4; ++g)
          acc[m][g] = __builtin_amdgcn_mfma_f32_16x16x32_bf16(af[m], bA[g], acc[m][g], 0, 0, 0);
    }
    {  // odd step: compute bB, prefetch bA
      const int step = 2 * s2 + 1;
      if (step < 15) {
#pragma unroll
        for (int g = 0; g < 4; ++g)
          bA[g] = *(const bf16x8*)(wp + g * 65536 + (step + 1) * 512);
      }
      bf16x8 af[4];
#pragma unroll
      for (int m = 0; m < 4; ++m) {
        int row = m * 16 + l15;
        int cl = (step * 4 + q) ^ (row & 7);
        af[m] = *(const bf16x8*)(As + (row * 64 + cl) * 8);
      }
#pragma unroll
      for (int m = 0; m < 4; ++m)
#pragma unroll
        for (int g = 0; g < 4; ++g)
          acc[m][g] = __builtin_amdgcn_mfma_f32_16x16x32_bf16(af[m], bB[g], acc[m][g], 0, 0, 0);
    }
  }

  // epilogue: LSTM cell math, fused
  const int o = w * 16 + l15;
  const float wci = w_ci[o], wcf = w_cf[o], wco = w_co[o];
  const float bi = b_i[o], bfv = b_f[o], bc = b_c[o], bo = b_o[o];
#pragma unroll
  for (int m = 0; m < 4; ++m) {
#pragma unroll
    for (int r = 0; r < 4; ++r) {
      int row = m0 + m * 16 + q * 4 + r;
      if (row < N_NODES) {
        float cv = c[(size_t)row * D + o];
        float ig = sigm(acc[m][0][r] + wci * cv + bi);
        float fg = sigm(acc[m][1][r] + wcf * cv + bfv);
        float ct = tanh_fast(acc[m][2][r] + bc);
        float nc = fg * cv + ig * ct;
        float og = sigm(acc[m][3][r] + wco * nc + bo);
        out_h[(size_t)row * D + o] = og * tanh_fast(nc);
        out_c[(size_t)row * D + o] = nc;
      }
    }
  }
}

extern "C" void kernel_launch(void* const* d_in, const int* in_sizes, int n_in,
                              void* d_out, int out_size, void* d_ws, size_t ws_size,
                              hipStream_t stream) {
  const float* x = (const float*)d_in[0];
  const float* h = (const float*)d_in[1];
  const float* c = (const float*)d_in[2];
  const float* Wx_self = (const float*)d_in[3];
  const float* Wx_neigh = (const float*)d_in[4];
  const float* Wh_self = (const float*)d_in[5];
  const float* Wh_neigh = (const float*)d_in[6];
  const float* w_ci = (const float*)d_in[7];
  const float* w_cf = (const float*)d_in[8];
  const float* w_co = (const float*)d_in[9];
  const float* b_i = (const float*)d_in[10];
  const float* b_f = (const float*)d_in[11];
  const float* b_c = (const float*)d_in[12];
  const float* b_o = (const float*)d_in[13];
  const int* src = (const int*)d_in[14];
  const int* dst = (const int*)d_in[15];

  char* ws = (char*)d_ws;
  int* deg = (int*)(ws);                    // 50000 ints
  int* offs = (int*)(ws + 200704);          // 50001 ints
  int* cursor = (int*)(ws + 400896);        // 50000 ints
  int* bins = (int*)(ws + 601088);          // 800000 ints
  __bf16* XH = (__bf16*)(ws + 4194304);     // [50048][256] bf16 = 25.6 MB
  __bf16* ZM = (__bf16*)(ws + 29818880);    // [50048][256] bf16 = 25.6 MB
  __bf16* Wp = (__bf16*)(ws + 55443456);    // [262144] bf16 frag-major

  float* out_h = (float*)d_out;
  float* out_c = out_h + (size_t)N_NODES * D;

  hipMemsetAsync(deg, 0, N_NODES * sizeof(int), stream);
  k_pre<<<NB_DEG + NB_TOB + NB_PKW, 256, 0, stream>>>(dst, deg, x, h, XH,
                                                      Wx_self, Wx_neigh, Wh_self, Wh_neigh, Wp);
  k_scan<<<1, 1024, 0, stream>>>(deg, offs, cursor, N_NODES);
  k_fill<<<(N_EDGES + 255) / 256, 256, 0, stream>>>(src, dst, cursor, bins);
  k_gather<<<NPAD / 4, 256, 0, stream>>>(offs, bins, XH, ZM);
  k_gemm<<<NPAD / 64, 512, 0, stream>>>(XH, ZM, Wp, c, w_ci, w_cf, w_co,
                                        b_i, b_f, b_c, b_o, out_h, out_c);
}

// Round 7
// 219.069 us; speedup vs baseline: 1.5213x; 1.0462x over previous
//
#include <hip/hip_runtime.h>
#include <hip/hip_bf16.h>
#include <stdint.h>

#define N_NODES 50000
#define N_EDGES 800000
#define D 128
#define NPAD 50048
#define HKD 256   // XH8/ZM col count
#define KDIM 512

typedef __attribute__((ext_vector_type(8))) __bf16 bf16x8;
typedef __attribute__((ext_vector_type(4))) __bf16 bf16x4;
typedef __attribute__((ext_vector_type(4))) float f32x4;
typedef __attribute__((ext_vector_type(2))) float f32x2;

__device__ __forceinline__ void gload_lds16(const void* g, void* l) {
  __builtin_amdgcn_global_load_lds(
      (const __attribute__((address_space(1))) unsigned int*)(uintptr_t)g,
      (__attribute__((address_space(3))) unsigned int*)(uint32_t)(uintptr_t)l,
      16, 0, 0);
}

__device__ __forceinline__ float sigm(float v) { return 1.0f / (1.0f + __expf(-v)); }
__device__ __forceinline__ float tanh_fast(float v) { return 1.0f - 2.0f / (1.0f + __expf(2.0f * v)); }

// ---- fp8 e4m3 (OCP) pack/unpack via gfx950 HW converts (fallback: hip_fp8 API) ----
#if defined(__has_builtin) && __has_builtin(__builtin_amdgcn_cvt_pk_fp8_f32) && __has_builtin(__builtin_amdgcn_cvt_pk_f32_fp8)
__device__ __forceinline__ unsigned pack_fp8x4(float a, float b, float c, float d) {
  int p = __builtin_amdgcn_cvt_pk_fp8_f32(a, b, 0, false);
  p = __builtin_amdgcn_cvt_pk_fp8_f32(c, d, p, true);
  return (unsigned)p;
}
__device__ __forceinline__ f32x2 unpk_fp8_lo(unsigned u) { return __builtin_amdgcn_cvt_pk_f32_fp8(u, false); }
__device__ __forceinline__ f32x2 unpk_fp8_hi(unsigned u) { return __builtin_amdgcn_cvt_pk_f32_fp8(u, true); }
#else
#include <hip/hip_fp8.h>
__device__ __forceinline__ unsigned pack_fp8x4(float a, float b, float c, float d) {
  __hip_fp8_e4m3 qa(a), qb(b), qc(c), qd(d);
  return (unsigned)qa.__x | ((unsigned)qb.__x << 8) | ((unsigned)qc.__x << 16) | ((unsigned)qd.__x << 24);
}
__device__ __forceinline__ float unpk1(unsigned byte) {
  __hip_fp8_e4m3 t; t.__x = (__hip_fp8_storage_t)byte; return (float)t;
}
__device__ __forceinline__ f32x2 unpk_fp8_lo(unsigned u) { f32x2 r; r.x = unpk1(u & 0xff); r.y = unpk1((u >> 8) & 0xff); return r; }
__device__ __forceinline__ f32x2 unpk_fp8_hi(unsigned u) { f32x2 r; r.x = unpk1((u >> 16) & 0xff); r.y = unpk1(u >> 24); return r; }
#endif

// ---------------- merged prep: deg count + fp32 -> fp8 XH8 + weight pack ----------------
// XH8 row (256 B): [ x(0-127) | h(128-255) ]
// Wp frag-major: idx = ((G*16 + step)*64 + q*16 + r16)*8 + e ; wrow = G*16+r16 = gate*128+o,
//   k = step*32 + q*8 + e ; k<128 Wx_self, <256 Wh_self, <384 Wx_neigh, else Wh_neigh
#define NB_DEG 3125   // 800000/256
#define NB_TOB 6250   // 1600000/256
#define NB_PKW 1024   // 262144/256
__global__ void k_pre(const int* __restrict__ dst, int* __restrict__ deg,
                      const float* __restrict__ x, const float* __restrict__ h,
                      uint8_t* __restrict__ XH8,
                      const float* __restrict__ Wx_self, const float* __restrict__ Wx_neigh,
                      const float* __restrict__ Wh_self, const float* __restrict__ Wh_neigh,
                      __bf16* __restrict__ Wp) {
  int b = blockIdx.x;
  if (b < NB_DEG) {
    int e = b * 256 + threadIdx.x;
    atomicAdd(&deg[dst[e]], 1);  // grid exact: 3125*256 == 800000
  } else if (b < NB_DEG + NB_TOB) {
    int idx = (b - NB_DEG) * 256 + threadIdx.x;  // 1.6M threads, 4 feats each
    int node = idx >> 5;
    int f4 = (idx & 31) << 2;
    float4 xv = *(const float4*)(x + (size_t)node * D + f4);
    float4 hv = *(const float4*)(h + (size_t)node * D + f4);
    uint8_t* r = XH8 + (size_t)node * HKD;
    *(unsigned*)(r + f4) = pack_fp8x4(xv.x, xv.y, xv.z, xv.w);
    *(unsigned*)(r + 128 + f4) = pack_fp8x4(hv.x, hv.y, hv.z, hv.w);
  } else {
    int idx = (b - NB_DEG - NB_TOB) * 256 + threadIdx.x;  // 0..262143
    int e = idx & 7;
    int r16 = (idx >> 3) & 15;
    int q = (idx >> 7) & 3;
    int s = (idx >> 9) & 15;
    int G = idx >> 13;           // 0..31
    int wrow = G * 16 + r16;     // gate*128 + o
    int g = wrow >> 7, o = wrow & 127;
    int k = s * 32 + q * 8 + e;
    const float* src; int i;
    if (k < 128)      { src = Wx_self;  i = k; }
    else if (k < 256) { src = Wh_self;  i = k - 128; }
    else if (k < 384) { src = Wx_neigh; i = k - 256; }
    else              { src = Wh_neigh; i = k - 384; }
    Wp[idx] = (__bf16)src[(g << 14) + (i << 7) + o];
  }
}

// ---------------- single-block exclusive scan (50000 ints, 1024 thr) ----------------
__global__ __launch_bounds__(1024) void k_scan(const int* __restrict__ deg, int* __restrict__ offs,
                                               int* __restrict__ cursor, int n) {
  const int t = threadIdx.x;
  const int lane = t & 63;
  const int w = t >> 6;  // 0..15
  __shared__ int wsum[16];
  __shared__ int carry_s;
  int carry = 0;
  for (int base = 0; base < n; base += 4096) {
    int idx = base + t * 4;
    int4 v = make_int4(0, 0, 0, 0);
    if (idx < n) v = *(const int4*)(deg + idx);
    int tsum = v.x + v.y + v.z + v.w;
    int s = tsum;
#pragma unroll
    for (int d = 1; d < 64; d <<= 1) {
      int u = __shfl_up(s, d, 64);
      if (lane >= d) s += u;
    }
    if (lane == 63) wsum[w] = s;
    __syncthreads();
    int woff = 0;
    for (int i = 0; i < w; i++) woff += wsum[i];
    int excl = carry + woff + (s - tsum);
    if (idx < n) {
      int4 o;
      o.x = excl; o.y = excl + v.x; o.z = o.y + v.y; o.w = o.z + v.z;
      *(int4*)(offs + idx) = o;
      *(int4*)(cursor + idx) = o;
    }
    __syncthreads();
    if (t == 0) {
      int tot = carry;
#pragma unroll
      for (int i = 0; i < 16; i++) tot += wsum[i];
      carry_s = tot;
    }
    __syncthreads();
    carry = carry_s;
  }
  if (t == 0) offs[n] = carry;
}

// ---------------- fill CSR bins ----------------
__global__ void k_fill(const int* __restrict__ src, const int* __restrict__ dst,
                       int* __restrict__ cursor, int* __restrict__ bins) {
  int e = blockIdx.x * 256 + threadIdx.x;
  if (e < N_EDGES) {
    int d = dst[e];
    int p = atomicAdd(&cursor[d], 1);
    bins[p] = src[e];
  }
}

// ---------------- gather means from fp8 rows: 1 wave/node, 8 edges in flight ----------------
// reads XH8 rows (256 B), writes ZM row bf16: [ mean_x(0-127) | mean_h(128-255) ]
__global__ void k_gather(const int* __restrict__ offs, const int* __restrict__ bins,
                         const uint8_t* __restrict__ XH8, __bf16* __restrict__ ZM) {
  int wid = (blockIdx.x * 256 + threadIdx.x) >> 6;
  int lane = threadIdx.x & 63;
  if (wid >= NPAD) return;
  if (wid >= N_NODES) {  // zero ZM pad rows (512 B, 64 lanes x 8B)
    ((uint2*)(ZM + (size_t)wid * HKD))[lane] = make_uint2(0, 0);
    return;
  }
  const int half = lane >> 5;
  const int li = lane & 31;
  const int boff = li * 8;  // byte offset into the 256B row (cols li*8..+7)
  int beg = offs[wid], end = offs[wid + 1];
  float a[8] = {0.f, 0.f, 0.f, 0.f, 0.f, 0.f, 0.f, 0.f};
  auto acc = [&](uint2 v) {
    f32x2 p;
    p = unpk_fp8_lo(v.x); a[0] += p.x; a[1] += p.y;
    p = unpk_fp8_hi(v.x); a[2] += p.x; a[3] += p.y;
    p = unpk_fp8_lo(v.y); a[4] += p.x; a[5] += p.y;
    p = unpk_fp8_hi(v.y); a[6] += p.x; a[7] += p.y;
  };
  int j = beg + half;
  for (; j + 6 < end; j += 8) {  // 4 edges in flight per half-wave
    int s0 = bins[j], s1 = bins[j + 2], s2 = bins[j + 4], s3 = bins[j + 6];
    uint2 v0 = *(const uint2*)(XH8 + (size_t)s0 * HKD + boff);
    uint2 v1 = *(const uint2*)(XH8 + (size_t)s1 * HKD + boff);
    uint2 v2 = *(const uint2*)(XH8 + (size_t)s2 * HKD + boff);
    uint2 v3 = *(const uint2*)(XH8 + (size_t)s3 * HKD + boff);
    acc(v0); acc(v1); acc(v2); acc(v3);
  }
  for (; j < end; j += 2) {
    uint2 v = *(const uint2*)(XH8 + (size_t)bins[j] * HKD + boff);
    acc(v);
  }
#pragma unroll
  for (int e = 0; e < 8; ++e) a[e] += __shfl_xor(a[e], 32, 64);
  int degn = end - beg;
  float inv = 1.0f / (float)(degn > 0 ? degn : 1);
  if (lane < 32) {
    bf16x8 bb;
#pragma unroll
    for (int e = 0; e < 8; ++e) bb[e] = (__bf16)(a[e] * inv);
    *(bf16x8*)(ZM + (size_t)wid * HKD + boff) = bb;
  }
}

// ---------------- fused GEMM + LSTM epilogue: barrier-free K-loop ----------------
// 512 thr / 8 waves, BM=64, BN=512. LDS (64KB) split: self half slots [0,2048) staged from
// fp32 x,h (reg+cvt+ds_write, per-lane swizzled dest), ZM half slots [2048,4096) via
// global_load_lds (linear dest, inverse-swizzled source). One barrier, then 16 K-steps of
// {global B-frag prefetch, ds_read A, setprio-wrapped MFMA}.
__global__ __launch_bounds__(512, 4) void k_gemm(
    const float* __restrict__ xg, const float* __restrict__ hg,
    const __bf16* __restrict__ ZM, const __bf16* __restrict__ Wp,
    const float* __restrict__ c,
    const float* __restrict__ w_ci, const float* __restrict__ w_cf, const float* __restrict__ w_co,
    const float* __restrict__ b_i, const float* __restrict__ b_f, const float* __restrict__ b_c,
    const float* __restrict__ b_o,
    float* __restrict__ out_h, float* __restrict__ out_c) {
  __shared__ __align__(16) __bf16 As[4096 * 8];  // 64 KB; slot = 16B chunk
  const int t = threadIdx.x;
  const int lane = t & 63;
  const int w = t >> 6;  // 0..7
  const int m0 = blockIdx.x * 64;
  const int l15 = lane & 15;
  const int q = lane >> 4;  // 0..3

  // ---- ZM half (k 256-511): async DMA, linear LDS dest, source chunk inverse-swizzled ----
#pragma unroll
  for (int i = 0; i < 4; ++i) {
    int u = i * 512 + t;           // 0..2047
    int row = u >> 5, cz = u & 31;
    int cg = cz ^ (row & 7);       // source chunk within ZM row
    gload_lds16(ZM + (size_t)(m0 + row) * HKD + cg * 8, (__bf16*)As + (2048 + u) * 8);
  }
  // ---- self half (k 0-255): fp32 -> bf16 reg-staged, swizzled ds_write ----
#pragma unroll
  for (int i = 0; i < 4; ++i) {
    int u = i * 512 + t;
    int row = u >> 5, cs = u & 31;
    int slot = row * 32 + (cs ^ (row & 7));
    int grow = m0 + row;
    bf16x8 val;
#pragma unroll
    for (int e = 0; e < 8; ++e) val[e] = (__bf16)0.f;
    if (grow < N_NODES) {
      const float* sp = (cs < 16) ? (xg + (size_t)grow * D + cs * 8)
                                  : (hg + (size_t)grow * D + (cs - 16) * 8);
      float4 u0 = *(const float4*)sp;
      float4 u1 = *(const float4*)(sp + 4);
      val[0] = (__bf16)u0.x; val[1] = (__bf16)u0.y; val[2] = (__bf16)u0.z; val[3] = (__bf16)u0.w;
      val[4] = (__bf16)u1.x; val[5] = (__bf16)u1.y; val[6] = (__bf16)u1.z; val[7] = (__bf16)u1.w;
    }
    *(bf16x8*)((__bf16*)As + slot * 8) = val;
  }
  __syncthreads();  // ONLY barrier

  f32x4 acc[4][4];
#pragma unroll
  for (int m = 0; m < 4; ++m)
#pragma unroll
    for (int g = 0; g < 4; ++g) acc[m][g] = (f32x4){0.f, 0.f, 0.f, 0.f};

  // B frag: frag g, step s -> Wp + ((g*8 + w)*16 + s)*512 + lane*8 (1KB contiguous per wave)
  const __bf16* wp = Wp + (size_t)(w * 16) * 512 + lane * 8;

  auto LOADA = [&](int step, bf16x8* af) {
    const int base = (step < 8) ? 0 : 2048;
    const int cq = ((step < 8) ? step * 4 : (step - 8) * 4) + q;
#pragma unroll
    for (int m = 0; m < 4; ++m) {
      int row = m * 16 + l15;
      af[m] = *(const bf16x8*)((__bf16*)As + (base + row * 32 + (cq ^ (row & 7))) * 8);
    }
  };

  bf16x8 bA[4], bB[4];
#pragma unroll
  for (int g = 0; g < 4; ++g) bA[g] = *(const bf16x8*)(wp + g * 65536);

#pragma unroll
  for (int s2 = 0; s2 < 8; ++s2) {
    {  // even step: compute bA, prefetch bB
      const int step = 2 * s2;
#pragma unroll
      for (int g = 0; g < 4; ++g)
        bB[g] = *(const bf16x8*)(wp + g * 65536 + (step + 1) * 512);
      bf16x8 af[4];
      LOADA(step, af);
      __builtin_amdgcn_s_setprio(1);
#pragma unroll
      for (int m = 0; m < 4; ++m)
#pragma unroll
        for (int g = 0; g < 4; ++g)
          acc[m][g] = __builtin_amdgcn_mfma_f32_16x16x32_bf16(af[m], bA[g], acc[m][g], 0, 0, 0);
      __builtin_amdgcn_s_setprio(0);
    }
    {  // odd step: compute bB, prefetch bA
      const int step = 2 * s2 + 1;
      if (step < 15) {
#pragma unroll
        for (int g = 0; g < 4; ++g)
          bA[g] = *(const bf16x8*)(wp + g * 65536 + (step + 1) * 512);
      }
      bf16x8 af[4];
      LOADA(step, af);
      __builtin_amdgcn_s_setprio(1);
#pragma unroll
      for (int m = 0; m < 4; ++m)
#pragma unroll
        for (int g = 0; g < 4; ++g)
          acc[m][g] = __builtin_amdgcn_mfma_f32_16x16x32_bf16(af[m], bB[g], acc[m][g], 0, 0, 0);
      __builtin_amdgcn_s_setprio(0);
    }
  }

  // epilogue: LSTM cell math, fused
  const int o = w * 16 + l15;
  const float wci = w_ci[o], wcf = w_cf[o], wco = w_co[o];
  const float bi = b_i[o], bfv = b_f[o], bc = b_c[o], bo = b_o[o];
#pragma unroll
  for (int m = 0; m < 4; ++m) {
#pragma unroll
    for (int r = 0; r < 4; ++r) {
      int row = m0 + m * 16 + q * 4 + r;
      if (row < N_NODES) {
        float cv = c[(size_t)row * D + o];
        float ig = sigm(acc[m][0][r] + wci * cv + bi);
        float fg = sigm(acc[m][1][r] + wcf * cv + bfv);
        float ct = tanh_fast(acc[m][2][r] + bc);
        float nc = fg * cv + ig * ct;
        float og = sigm(acc[m][3][r] + wco * nc + bo);
        out_h[(size_t)row * D + o] = og * tanh_fast(nc);
        out_c[(size_t)row * D + o] = nc;
      }
    }
  }
}

extern "C" void kernel_launch(void* const* d_in, const int* in_sizes, int n_in,
                              void* d_out, int out_size, void* d_ws, size_t ws_size,
                              hipStream_t stream) {
  const float* x = (const float*)d_in[0];
  const float* h = (const float*)d_in[1];
  const float* c = (const float*)d_in[2];
  const float* Wx_self = (const float*)d_in[3];
  const float* Wx_neigh = (const float*)d_in[4];
  const float* Wh_self = (const float*)d_in[5];
  const float* Wh_neigh = (const float*)d_in[6];
  const float* w_ci = (const float*)d_in[7];
  const float* w_cf = (const float*)d_in[8];
  const float* w_co = (const float*)d_in[9];
  const float* b_i = (const float*)d_in[10];
  const float* b_f = (const float*)d_in[11];
  const float* b_c = (const float*)d_in[12];
  const float* b_o = (const float*)d_in[13];
  const int* src = (const int*)d_in[14];
  const int* dst = (const int*)d_in[15];

  char* ws = (char*)d_ws;
  int* deg = (int*)(ws);                       // 50000 ints
  int* offs = (int*)(ws + 200704);             // 50001 ints
  int* cursor = (int*)(ws + 400896);           // 50000 ints
  int* bins = (int*)(ws + 601088);             // 800000 ints (ends 3,801,088)
  uint8_t* XH8 = (uint8_t*)(ws + 4194304);     // [50048][256] fp8 = 12.8 MB (ends 17,006,592)
  __bf16* ZM = (__bf16*)(ws + 17039360);       // [50048][256] bf16 = 25.6 MB (ends 42,663,936)
  __bf16* Wp = (__bf16*)(ws + 42729472);       // [262144] bf16 frag-major (ends 43,253,760)

  float* out_h = (float*)d_out;
  float* out_c = out_h + (size_t)N_NODES * D;

  hipMemsetAsync(deg, 0, N_NODES * sizeof(int), stream);
  k_pre<<<NB_DEG + NB_TOB + NB_PKW, 256, 0, stream>>>(dst, deg, x, h, XH8,
                                                      Wx_self, Wx_neigh, Wh_self, Wh_neigh, Wp);
  k_scan<<<1, 1024, 0, stream>>>(deg, offs, cursor, N_NODES);
  k_fill<<<(N_EDGES + 255) / 256, 256, 0, stream>>>(src, dst, cursor, bins);
  k_gather<<<NPAD / 4, 256, 0, stream>>>(offs, bins, XH8, ZM);
  k_gemm<<<NPAD / 64, 512, 0, stream>>>(x, h, ZM, Wp, c, w_ci, w_cf, w_co,
                                        b_i, b_f, b_c, b_o, out_h, out_c);
}